// Round 4
// baseline (998.422 us; speedup 1.0000x reference)
//
#include <hip/hip_runtime.h>
#include <hip/hip_bf16.h>

#define NRELS 8
#define NB 8
#define SCAN_B 1024

typedef __attribute__((ext_vector_type(8))) short short8v;
typedef __attribute__((ext_vector_type(4))) float f32x4;

__device__ __forceinline__ short bfc(float f) {
    __hip_bfloat16 h = __float2bfloat16(f);
    return *reinterpret_cast<short*>(&h);
}

// ---- W in MFMA B-fragment order (bf16), same layout as R3 (verified).
__global__ void wprep_kernel(const float* __restrict__ basis1, const float* __restrict__ comp1,
                             const float* __restrict__ basis2, const float* __restrict__ comp2,
                             short* __restrict__ Wf1, short* __restrict__ Wf2) {
    int idx = blockIdx.x * blockDim.x + threadIdx.x;
    const int n1 = NRELS * 8 * 64 * 8;
    const int n2 = NRELS * 4 * 64 * 8;
    if (idx < n1) {
        int r = idx >> 12, f = (idx >> 9) & 7, lane = (idx >> 3) & 63, j = idx & 7;
        int k = (f & 1) * 32 + (lane >> 4) * 8 + j;
        int n = (f >> 1) * 16 + (lane & 15);
        float s = 0.f;
#pragma unroll
        for (int b = 0; b < NB; ++b)
            s = fmaf(comp1[r * NB + b], basis1[b * 4096 + k * 64 + n], s);
        Wf1[idx] = bfc(s);
    } else if (idx < n1 + n2) {
        int j2 = idx - n1;
        int r = j2 >> 11, f = (j2 >> 9) & 3, lane = (j2 >> 3) & 63, j = j2 & 7;
        int k = (f & 1) * 32 + (lane >> 4) * 8 + j;
        int n = (f >> 1) * 16 + (lane & 15);
        float s = 0.f;
#pragma unroll
        for (int b = 0; b < NB; ++b)
            s = fmaf(comp2[r * NB + b], basis2[b * 2048 + k * 32 + n], s);
        Wf2[j2] = bfc(s);
    }
}

__global__ void init_kernel(const float* __restrict__ bias1, const float* __restrict__ bias2,
                            float* __restrict__ h1, float* __restrict__ out, int nNodes) {
    int n1 = nNodes * 64;
    int total = nNodes * (64 + 32);
    for (int idx = blockIdx.x * blockDim.x + threadIdx.x; idx < total;
         idx += gridDim.x * blockDim.x) {
        if (idx < n1) h1[idx] = bias1[idx & 63];
        else          out[idx - n1] = bias2[(idx - n1) & 31];
    }
}

// fp32 -> bf16 (vector x4)
__global__ void cvt_kernel(const float* __restrict__ in, ushort* __restrict__ outb, int n4) {
    for (int i = blockIdx.x * blockDim.x + threadIdx.x; i < n4;
         i += gridDim.x * blockDim.x) {
        float4 v = reinterpret_cast<const float4*>(in)[i];
        ushort4 o;
        o.x = (ushort)bfc(v.x); o.y = (ushort)bfc(v.y);
        o.z = (ushort)bfc(v.z); o.w = (ushort)bfc(v.w);
        reinterpret_cast<ushort4*>(outb)[i] = o;
    }
}

// ---- counting sort by dst ----
__global__ void hist2_kernel(const int* __restrict__ dst, int* __restrict__ cnt, int n) {
    for (int i = blockIdx.x * blockDim.x + threadIdx.x; i < n;
         i += gridDim.x * blockDim.x)
        atomicAdd(&cnt[dst[i]], 1);
}

__global__ void scan1_kernel(const int* __restrict__ cnt, int* __restrict__ part, int n) {
    __shared__ int sh[SCAN_B];
    int i = blockIdx.x * SCAN_B + threadIdx.x;
    sh[threadIdx.x] = (i < n) ? cnt[i] : 0;
    __syncthreads();
    for (int s = SCAN_B / 2; s > 0; s >>= 1) {
        if (threadIdx.x < s) sh[threadIdx.x] += sh[threadIdx.x + s];
        __syncthreads();
    }
    if (threadIdx.x == 0) part[blockIdx.x] = sh[0];
}

__global__ void scan2_kernel(int* __restrict__ part, int nb) {   // 1 block, 256 thr
    __shared__ int sh[256];
    int v = (threadIdx.x < nb) ? part[threadIdx.x] : 0;
    sh[threadIdx.x] = v;
    __syncthreads();
    for (int s = 1; s < 256; s <<= 1) {
        int t = (threadIdx.x >= s) ? sh[threadIdx.x - s] : 0;
        __syncthreads();
        sh[threadIdx.x] += t;
        __syncthreads();
    }
    if (threadIdx.x < nb) part[threadIdx.x] = sh[threadIdx.x] - v;   // exclusive
}

__global__ void scan3_kernel(const int* __restrict__ cnt, const int* __restrict__ part,
                             int* __restrict__ run, int n) {
    __shared__ int sh[SCAN_B];
    int i = blockIdx.x * SCAN_B + threadIdx.x;
    int v = (i < n) ? cnt[i] : 0;
    sh[threadIdx.x] = v;
    __syncthreads();
    for (int s = 1; s < SCAN_B; s <<= 1) {
        int t = (threadIdx.x >= s) ? sh[threadIdx.x - s] : 0;
        __syncthreads();
        sh[threadIdx.x] += t;
        __syncthreads();
    }
    if (i < n) run[i] = part[blockIdx.x] + sh[threadIdx.x] - v;
}

__global__ void scatter2_kernel(const int* __restrict__ src, const int* __restrict__ dst,
                                const int* __restrict__ et, const float* __restrict__ norm,
                                int* __restrict__ run, int* __restrict__ srcd,
                                int* __restrict__ dstd, int* __restrict__ rtd,
                                float* __restrict__ normd, int n) {
    for (int i = blockIdx.x * blockDim.x + threadIdx.x; i < n;
         i += gridDim.x * blockDim.x) {
        int d = dst[i];
        int p = atomicAdd(&run[d], 1);
        srcd[p] = src[i];
        dstd[p] = d;
        rtd[p] = et[i];
        normd[p] = norm[i];
    }
}

// ---- masked-MFMA edge layer on dst-sorted edges ----
// One wave = 16-edge tile (mixed relations). Per present relation: cndmask A rows,
// accumulate MFMA into shared acc (exact: masked rows contribute 0). Atomic scatter
// targets are dst-clustered -> each h1 line stays resident in one XCD's L2.
template <int OUT>
__global__ __launch_bounds__(256, 4) void layer_kernel(
    const ushort* __restrict__ xb, const short* __restrict__ Wf,
    const int* __restrict__ srcd, const int* __restrict__ dstd,
    const int* __restrict__ rtd, const float* __restrict__ normd,
    float* __restrict__ out, int nTiles, int T) {
    constexpr int NT = OUT / 16;
    constexpr int NF = NT * 2;
    const int lane = threadIdx.x & 63;
    const int wid = (blockIdx.x * blockDim.x + threadIdx.x) >> 6;
    const int ml = lane & 15;
    const int kg = lane >> 4;
    const int t0 = wid * T;
    const int t1 = min(t0 + T, nTiles);
    if (t0 >= t1) return;

    const short8v zero8 = {0, 0, 0, 0, 0, 0, 0, 0};

    // meta tile t0
    int e = (t0 << 4) + ml;
    int sv = srcd[e], dv = dstd[e], rv = rtd[e];
    float nv = normd[e];
    // A rows tile t0 (bf16: row = 128B, lane loads 16B at k-slice kg*8)
    const ushort* xp = xb + (size_t)sv * 64 + kg * 8;
    short8v a0 = *(const short8v*)xp;
    short8v a1 = *(const short8v*)(xp + 32);
    // meta tile t0+1
    int sv2 = 0, dv2 = 0, rv2 = 0;
    float nv2 = 0.f;
    if (t0 + 1 < t1) {
        int e2 = ((t0 + 1) << 4) + ml;
        sv2 = srcd[e2]; dv2 = dstd[e2]; rv2 = rtd[e2]; nv2 = normd[e2];
    }

    for (int t = t0; t < t1; ++t) {
        short8v A0 = a0, A1 = a1;
        if (t + 1 < t1) {   // prefetch next tile's A rows
            const ushort* xq = xb + (size_t)sv2 * 64 + kg * 8;
            a0 = *(const short8v*)xq;
            a1 = *(const short8v*)(xq + 32);
        }
        f32x4 acc[NT];
#pragma unroll
        for (int nt = 0; nt < NT; ++nt) acc[nt] = (f32x4){0.f, 0.f, 0.f, 0.f};

#pragma unroll
        for (int r = 0; r < NRELS; ++r) {
            if (__ballot(rv == r) == 0ull) continue;
            bool c = (rv == r);
            short8v Am0 = c ? A0 : zero8;
            short8v Am1 = c ? A1 : zero8;
            const short* wp = Wf + (((size_t)r * NF) * 64 + lane) * 8;
#pragma unroll
            for (int nt = 0; nt < NT; ++nt) {
                short8v B0 = *(const short8v*)(wp + (nt * 2 + 0) * 512);
                short8v B1 = *(const short8v*)(wp + (nt * 2 + 1) * 512);
                acc[nt] = __builtin_amdgcn_mfma_f32_16x16x32_bf16(Am0, B0, acc[nt], 0, 0, 0);
                acc[nt] = __builtin_amdgcn_mfma_f32_16x16x32_bf16(Am1, B1, acc[nt], 0, 0, 0);
            }
        }
        // epilogue: D row = kg*4+i (edge), col = nt*16+ml
#pragma unroll
        for (int i = 0; i < 4; ++i) {
            int row = kg * 4 + i;
            int d = __shfl(dv, row);
            float nm = __shfl(nv, row);
            float* ob = out + (size_t)d * OUT + ml;
#pragma unroll
            for (int nt = 0; nt < NT; ++nt)
                atomicAdd(ob + nt * 16, acc[nt][i] * nm);
        }
        // rotate meta pipeline
        sv = sv2; dv = dv2; rv = rv2; nv = nv2;
        if (t + 2 < t1) {
            int e3 = ((t + 2) << 4) + ml;
            sv2 = srcd[e3]; dv2 = dstd[e3]; rv2 = rtd[e3]; nv2 = normd[e3];
        }
    }
}

extern "C" void kernel_launch(void* const* d_in, const int* in_sizes, int n_in,
                              void* d_out, int out_size, void* d_ws, size_t ws_size,
                              hipStream_t stream) {
    const float* emb    = (const float*)d_in[0];
    const float* basis1 = (const float*)d_in[1];
    const float* comp1  = (const float*)d_in[2];
    const float* bias1  = (const float*)d_in[3];
    const float* basis2 = (const float*)d_in[4];
    const float* comp2  = (const float*)d_in[5];
    const float* bias2  = (const float*)d_in[6];
    const int*   src    = (const int*)d_in[7];
    const int*   dst    = (const int*)d_in[8];
    const int*   etype  = (const int*)d_in[9];
    const float* norm   = (const float*)d_in[10];
    float* out = (float*)d_out;

    const int nNodes = in_sizes[0] / 64;   // 200000
    const int nEdges = in_sizes[7];        // 1000000

    const int CAP = ((nEdges + 15) / 16) * 16;
    const size_t CAP4 = (((size_t)CAP * 4 + 255) / 256) * 256;
    const int nBins = ((nNodes + SCAN_B - 1) / SCAN_B) * SCAN_B;   // 200704
    const int nScanBlocks = nBins / SCAN_B;                        // 196 (<=256)

    char* ws = (char*)d_ws;
    short* Wf1   = (short*)(ws);                      // 65536
    short* Wf2   = (short*)(ws + 65536);              // 32768
    int*   part  = (int*)(ws + 98304);                // 1KB
    int*   cnt2  = (int*)(ws + 102400);               // nBins*4 (~803KB)
    size_t off = 1048576;
    int*   srcd  = (int*)(ws + off);
    int*   dstd  = (int*)(ws + off + CAP4);
    int*   rtd   = (int*)(ws + off + 2 * CAP4);
    float* normd = (float*)(ws + off + 3 * CAP4);
    size_t off2 = off + 4 * CAP4;
    ushort* embb = (ushort*)(ws + off2);                                  // 25.6MB
    float*  h1   = (float*)(ws + off2 + (size_t)nNodes * 64 * 2);         // 51.2MB
    ushort* h1b  = (ushort*)(ws + off2 + (size_t)nNodes * 64 * 2 + (size_t)nNodes * 64 * 4);

    // zero histogram bins (incl. padding)
    hipMemsetAsync(cnt2, 0, (size_t)nBins * 4, stream);
    // zero pad tail of sorted arrays if CAP > nEdges
    if (CAP > nEdges) {
        size_t tail = (size_t)(CAP - nEdges) * 4;
        hipMemsetAsync(srcd + nEdges, 0, tail, stream);
        hipMemsetAsync(dstd + nEdges, 0, tail, stream);
        hipMemsetAsync(rtd + nEdges, 0, tail, stream);
        hipMemsetAsync(normd + nEdges, 0, tail, stream);
    }

    wprep_kernel<<<(NRELS * 64 * (64 + 32) + 255) / 256, 256, 0, stream>>>(
        basis1, comp1, basis2, comp2, Wf1, Wf2);
    cvt_kernel<<<1024, 256, 0, stream>>>(emb, embb, nNodes * 16);
    init_kernel<<<4096, 256, 0, stream>>>(bias1, bias2, h1, out, nNodes);
    hist2_kernel<<<1024, 256, 0, stream>>>(dst, cnt2, nEdges);
    scan1_kernel<<<nScanBlocks, SCAN_B, 0, stream>>>(cnt2, part, nBins);
    scan2_kernel<<<1, 256, 0, stream>>>(part, nScanBlocks);
    scan3_kernel<<<nScanBlocks, SCAN_B, 0, stream>>>(cnt2, part, cnt2, nBins);
    scatter2_kernel<<<1024, 256, 0, stream>>>(src, dst, etype, norm, cnt2,
                                              srcd, dstd, rtd, normd, nEdges);

    const int nTiles = CAP / 16;
    const int nBlocks = 2048;
    const int nWaves = nBlocks * 4;
    const int T = (nTiles + nWaves - 1) / nWaves;
    layer_kernel<64><<<nBlocks, 256, 0, stream>>>(embb, Wf1, srcd, dstd, rtd, normd,
                                                  h1, nTiles, T);
    cvt_kernel<<<1024, 256, 0, stream>>>(h1, h1b, nNodes * 16);
    layer_kernel<32><<<nBlocks, 256, 0, stream>>>(h1b, Wf2, srcd, dstd, rtd, normd,
                                                  out, nTiles, T);
}

// Round 5
// 382.980 us; speedup vs baseline: 2.6070x; 2.6070x over previous
//
#include <hip/hip_runtime.h>
#include <hip/hip_bf16.h>

#define NRELS 8
#define NB 8
#define SCAN_B 1024

typedef __attribute__((ext_vector_type(8))) short short8v;
typedef __attribute__((ext_vector_type(4))) float f32x4;

__device__ __forceinline__ short bfc(float f) {
    __hip_bfloat16 h = __float2bfloat16(f);
    return *reinterpret_cast<short*>(&h);
}
__device__ __forceinline__ float bf2f(ushort u) {
    return __uint_as_float((unsigned)u << 16);
}
__device__ __forceinline__ short8v cvt8(float4 a, float4 b) {
    short8v r;
    r[0] = bfc(a.x); r[1] = bfc(a.y); r[2] = bfc(a.z); r[3] = bfc(a.w);
    r[4] = bfc(b.x); r[5] = bfc(b.y); r[6] = bfc(b.z); r[7] = bfc(b.w);
    return r;
}

// ---- W in MFMA B-frag order with even/odd column interleave for packed bf16 stores.
// Global macro gg covers 32 output cols: col = gg*32 + 2*(lane&15) + p.
// Wf1: gg in [0,16): r = gg>>1, c_rel = (gg&1)*32 + 2*ml + p  (OUT=64)
// Wf2: gg in [0,8):  r = gg,    c_rel = 2*ml + p              (OUT=32)
// frag f = gg*4 + p*2 + ks; element j: k = ks*32 + (lane>>4)*8 + j.
__global__ void wprep_kernel(const float* __restrict__ basis1, const float* __restrict__ comp1,
                             const float* __restrict__ basis2, const float* __restrict__ comp2,
                             short* __restrict__ Wf1, short* __restrict__ Wf2) {
    int idx = blockIdx.x * blockDim.x + threadIdx.x;
    const int n1 = 64 * 512;   // 32768
    const int n2 = 32 * 512;   // 16384
    if (idx < n1) {
        int f = idx >> 9, lane = (idx >> 3) & 63, j = idx & 7;
        int ks = f & 1, p = (f >> 1) & 1, gg = f >> 2;
        int r = gg >> 1;
        int c = (gg & 1) * 32 + 2 * (lane & 15) + p;
        int k = ks * 32 + (lane >> 4) * 8 + j;
        float s = 0.f;
#pragma unroll
        for (int b = 0; b < NB; ++b)
            s = fmaf(comp1[r * NB + b], basis1[b * 4096 + k * 64 + c], s);
        Wf1[idx] = bfc(s);
    } else if (idx < n1 + n2) {
        int i2 = idx - n1;
        int f = i2 >> 9, lane = (i2 >> 3) & 63, j = i2 & 7;
        int ks = f & 1, p = (f >> 1) & 1, gg = f >> 2;
        int r = gg;
        int c = 2 * (lane & 15) + p;
        int k = ks * 32 + (lane >> 4) * 8 + j;
        float s = 0.f;
#pragma unroll
        for (int b = 0; b < NB; ++b)
            s = fmaf(comp2[r * NB + b], basis2[b * 2048 + k * 32 + c], s);
        Wf2[i2] = bfc(s);
    }
}

__global__ void init_kernel(const float* __restrict__ bias1, const float* __restrict__ bias2,
                            float* __restrict__ h1, float* __restrict__ out, int nNodes) {
    int n1 = nNodes * 64;
    int total = nNodes * (64 + 32);
    for (int idx = blockIdx.x * blockDim.x + threadIdx.x; idx < total;
         idx += gridDim.x * blockDim.x) {
        if (idx < n1) h1[idx] = bias1[idx & 63];
        else          out[idx - n1] = bias2[(idx - n1) & 31];
    }
}

// ---- counting sort by dst ----
__global__ void hist2_kernel(const int* __restrict__ dst, int* __restrict__ cnt, int n) {
    for (int i = blockIdx.x * blockDim.x + threadIdx.x; i < n;
         i += gridDim.x * blockDim.x)
        atomicAdd(&cnt[dst[i]], 1);
}

__global__ void scan1_kernel(const int* __restrict__ cnt, int* __restrict__ part, int n) {
    __shared__ int sh[SCAN_B];
    int i = blockIdx.x * SCAN_B + threadIdx.x;
    sh[threadIdx.x] = (i < n) ? cnt[i] : 0;
    __syncthreads();
    for (int s = SCAN_B / 2; s > 0; s >>= 1) {
        if (threadIdx.x < s) sh[threadIdx.x] += sh[threadIdx.x + s];
        __syncthreads();
    }
    if (threadIdx.x == 0) part[blockIdx.x] = sh[0];
}

__global__ void scan2_kernel(int* __restrict__ part, int nb) {
    __shared__ int sh[256];
    int v = (threadIdx.x < nb) ? part[threadIdx.x] : 0;
    sh[threadIdx.x] = v;
    __syncthreads();
    for (int s = 1; s < 256; s <<= 1) {
        int t = (threadIdx.x >= s) ? sh[threadIdx.x - s] : 0;
        __syncthreads();
        sh[threadIdx.x] += t;
        __syncthreads();
    }
    if (threadIdx.x < nb) part[threadIdx.x] = sh[threadIdx.x] - v;   // exclusive
}

__global__ void scan3_kernel(const int* __restrict__ cnt, const int* __restrict__ part,
                             int* __restrict__ run, int n) {
    __shared__ int sh[SCAN_B];
    int i = blockIdx.x * SCAN_B + threadIdx.x;
    int v = (i < n) ? cnt[i] : 0;
    sh[threadIdx.x] = v;
    __syncthreads();
    for (int s = 1; s < SCAN_B; s <<= 1) {
        int t = (threadIdx.x >= s) ? sh[threadIdx.x - s] : 0;
        __syncthreads();
        sh[threadIdx.x] += t;
        __syncthreads();
    }
    if (i < n) run[i] = part[blockIdx.x] + sh[threadIdx.x] - v;
}

__global__ void scatter2_kernel(const int* __restrict__ src, const int* __restrict__ dst,
                                const int* __restrict__ et, const float* __restrict__ norm,
                                int* __restrict__ run, int4* __restrict__ meta, int n) {
    for (int i = blockIdx.x * blockDim.x + threadIdx.x; i < n;
         i += gridDim.x * blockDim.x) {
        int d = dst[i];
        int p = atomicAdd(&run[d], 1);
        meta[p] = make_int4(src[i], d, et[i], __float_as_int(norm[i]));
    }
}

// ---- dense transform GEMM: Y[n, gg*32 + 2*ml + p] = X[n,:] @ W  (bf16 out, packed dword)
// One wave = 64 nodes (4 MFMA sub-tiles of 16). A: coalesced fp32 loads + in-reg cvt.
// B: even/odd col fragments from L2-resident Wf. G macros of 32 cols.
template <int G>
__global__ __launch_bounds__(256) void transform_kernel(
    const float* __restrict__ x, const short* __restrict__ Wf,
    ushort* __restrict__ yb, int nNodes) {
    constexpr int TOUT = G * 32;
    const int lane = threadIdx.x & 63;
    const int wid = (blockIdx.x * blockDim.x + threadIdx.x) >> 6;
    const int base = wid * 64;
    if (base >= nNodes) return;
    const int ml = lane & 15, kg = lane >> 4;

    short8v A[4][2];
#pragma unroll
    for (int s = 0; s < 4; ++s) {
        const float* xp = x + (size_t)(base + s * 16 + ml) * 64 + kg * 8;
        float4 f0 = *(const float4*)xp;
        float4 f1 = *(const float4*)(xp + 4);
        float4 f2 = *(const float4*)(xp + 32);
        float4 f3 = *(const float4*)(xp + 36);
        A[s][0] = cvt8(f0, f1);
        A[s][1] = cvt8(f2, f3);
    }
#pragma unroll
    for (int gg = 0; gg < G; ++gg) {
        const short* wp = Wf + (size_t)gg * 4 * 512 + lane * 8;
        short8v Be0 = *(const short8v*)(wp);
        short8v Be1 = *(const short8v*)(wp + 512);
        short8v Bo0 = *(const short8v*)(wp + 1024);
        short8v Bo1 = *(const short8v*)(wp + 1536);
#pragma unroll
        for (int s = 0; s < 4; ++s) {
            f32x4 ae = __builtin_amdgcn_mfma_f32_16x16x32_bf16(A[s][0], Be0,
                                                               (f32x4){0.f, 0.f, 0.f, 0.f}, 0, 0, 0);
            ae = __builtin_amdgcn_mfma_f32_16x16x32_bf16(A[s][1], Be1, ae, 0, 0, 0);
            f32x4 ao = __builtin_amdgcn_mfma_f32_16x16x32_bf16(A[s][0], Bo0,
                                                               (f32x4){0.f, 0.f, 0.f, 0.f}, 0, 0, 0);
            ao = __builtin_amdgcn_mfma_f32_16x16x32_bf16(A[s][1], Bo1, ao, 0, 0, 0);
#pragma unroll
            for (int i = 0; i < 4; ++i) {
                unsigned lo = (unsigned)(ushort)bfc(ae[i]);
                unsigned hi = (unsigned)(ushort)bfc(ao[i]);
                unsigned pk = lo | (hi << 16);
                int row = base + s * 16 + kg * 4 + i;
                *reinterpret_cast<unsigned*>(yb + (size_t)row * TOUT + gg * 32 + ml * 2) = pk;
            }
        }
    }
}

// ---- edge aggregation: dst-sorted segmented sum, atomic-free interior writes.
// Group of OUT lanes owns edge range [e0,e1); per edge: gather pre-transformed
// row yb[src*rowStride + (rt-rtLo)*OUT + o], acc += norm*val; on dst change flush:
// interior run -> plain store (bias+acc | out+=acc), boundary run -> atomicAdd.
// Prefetch: meta 3 deep, gather 2 deep (breaks meta->gather serial chain).
template <int OUT, bool ADDMODE>
__global__ __launch_bounds__(256) void edge_kernel(
    const ushort* __restrict__ yb, const int4* __restrict__ meta,
    const float* __restrict__ bias, float* __restrict__ out,
    int nEdges, int chunk, int rtLo, int rtCnt, int rowStride) {
    const int lane = threadIdx.x & 63;
    constexpr int GPW = 64 / OUT;
    const int wid = (blockIdx.x * blockDim.x + threadIdx.x) >> 6;
    const int gid = wid * GPW + ((GPW == 2) ? (lane >> 5) : 0);
    const int o = lane & (OUT - 1);
    int e0 = gid * chunk;
    if (e0 >= nEdges) return;
    int e1 = e0 + chunk;
    if (e1 > nEdges) e1 = nEdges;

    const float bv = ADDMODE ? 0.f : bias[o];

    auto gather = [&](int4 mm) -> float {
        int rr = mm.z - rtLo;
        float v = 0.f;
        if ((unsigned)rr < (unsigned)rtCnt)
            v = bf2f(yb[(size_t)mm.x * rowStride + rr * OUT + o]);
        return v;
    };

    int eB = (e0 + 1 < e1) ? e0 + 1 : e1 - 1;
    int eC = (e0 + 2 < e1) ? e0 + 2 : e1 - 1;
    int4 M0 = meta[e0];
    int4 M1 = meta[eB];
    int4 M2 = meta[eC];
    float V0 = gather(M0);
    float V1 = gather(M1);

    bool headShared = (e0 > 0) && (meta[e0 - 1].y == M0.y);
    float acc = 0.f;
    int dcur = M0.y;
    bool firstRun = true;

    for (int e = e0; e < e1; ++e) {
        // issue-ahead: meta e+3, gather e+2
        int eD = (e + 3 < e1) ? e + 3 : e1 - 1;
        int4 M3 = meta[eD];
        float V2 = gather(M2);

        if (M0.y != dcur) {
            size_t idx = (size_t)dcur * OUT + o;
            if (firstRun && headShared) atomicAdd(out + idx, acc);
            else if (ADDMODE) out[idx] += acc;
            else out[idx] = bv + acc;
            acc = 0.f;
            firstRun = false;
            dcur = M0.y;
        }
        acc = fmaf(__int_as_float(M0.w), V0, acc);

        M0 = M1; M1 = M2; M2 = M3;
        V0 = V1; V1 = V2;
    }
    bool tailShared = (e1 < nEdges) && (meta[e1].y == dcur);
    size_t idx = (size_t)dcur * OUT + o;
    if ((firstRun && headShared) || tailShared) atomicAdd(out + idx, acc);
    else if (ADDMODE) out[idx] += acc;
    else out[idx] = bv + acc;
}

extern "C" void kernel_launch(void* const* d_in, const int* in_sizes, int n_in,
                              void* d_out, int out_size, void* d_ws, size_t ws_size,
                              hipStream_t stream) {
    const float* emb    = (const float*)d_in[0];
    const float* basis1 = (const float*)d_in[1];
    const float* comp1  = (const float*)d_in[2];
    const float* bias1  = (const float*)d_in[3];
    const float* basis2 = (const float*)d_in[4];
    const float* comp2  = (const float*)d_in[5];
    const float* bias2  = (const float*)d_in[6];
    const int*   src    = (const int*)d_in[7];
    const int*   dst    = (const int*)d_in[8];
    const int*   etype  = (const int*)d_in[9];
    const float* norm   = (const float*)d_in[10];
    float* out = (float*)d_out;

    const int nNodes = in_sizes[0] / 64;   // 200000
    const int nEdges = in_sizes[7];        // 1000000

    const int nBins = ((nNodes + SCAN_B - 1) / SCAN_B) * SCAN_B;   // 200704
    const int nScanBlocks = nBins / SCAN_B;                        // 196 (<=256)

    char* ws = (char*)d_ws;
    short* Wf1  = (short*)(ws);                      // 65536 B
    short* Wf2  = (short*)(ws + 65536);              // 32768 B
    int*   part = (int*)(ws + 98304);                // 1 KB
    int*   cnt2 = (int*)(ws + 102400);               // ~803 KB
    size_t offMeta = 1048576;
    int4*  meta = (int4*)(ws + offMeta);                              // 16 MB
    size_t offY = offMeta + (((size_t)nEdges * 16 + 255) & ~(size_t)255);
    ushort* yH  = (ushort*)(ws + offY);                               // 102.4 MB ([N,256] bf16)
    size_t offH1 = offY + (size_t)nNodes * 256 * 2;
    float* h1   = (float*)(ws + offH1);                               // 51.2 MB

    hipMemsetAsync(cnt2, 0, (size_t)nBins * 4, stream);

    wprep_kernel<<<192, 256, 0, stream>>>(basis1, comp1, basis2, comp2, Wf1, Wf2);
    init_kernel<<<4096, 256, 0, stream>>>(bias1, bias2, h1, out, nNodes);
    hist2_kernel<<<1024, 256, 0, stream>>>(dst, cnt2, nEdges);
    scan1_kernel<<<nScanBlocks, SCAN_B, 0, stream>>>(cnt2, part, nBins);
    scan2_kernel<<<1, 256, 0, stream>>>(part, nScanBlocks);
    scan3_kernel<<<nScanBlocks, SCAN_B, 0, stream>>>(cnt2, part, cnt2, nBins);
    scatter2_kernel<<<1024, 256, 0, stream>>>(src, dst, etype, norm, cnt2, meta, nEdges);

    const int tBlocks = ((nNodes + 63) / 64 + 3) / 4;   // 782
    const int eBlocks = 2048;                           // 8192 waves
    const int g64 = eBlocks * 4;                        // groups for OUT=64
    const int g32 = eBlocks * 8;                        // groups for OUT=32
    const int ch64 = (nEdges + g64 - 1) / g64;
    const int ch32 = (nEdges + g32 - 1) / g32;

    // ---- layer 1, relations 0-3 ----
    transform_kernel<8><<<tBlocks, 256, 0, stream>>>(emb, Wf1, yH, nNodes);
    edge_kernel<64, false><<<eBlocks, 256, 0, stream>>>(yH, meta, bias1, h1,
                                                        nEdges, ch64, 0, 4, 256);
    // ---- layer 1, relations 4-7 ----
    transform_kernel<8><<<tBlocks, 256, 0, stream>>>(emb, Wf1 + 16384, yH, nNodes);
    edge_kernel<64, true><<<eBlocks, 256, 0, stream>>>(yH, meta, bias1, h1,
                                                       nEdges, ch64, 4, 4, 256);
    // ---- layer 2 (all 8 relations, OUT=32) ----
    transform_kernel<8><<<tBlocks, 256, 0, stream>>>(h1, Wf2, yH, nNodes);
    edge_kernel<32, false><<<eBlocks, 256, 0, stream>>>(yH, meta, bias2, out,
                                                        nEdges, ch32, 0, 8, 256);
}

// Round 6
// 347.721 us; speedup vs baseline: 2.8713x; 1.1014x over previous
//
#include <hip/hip_runtime.h>
#include <hip/hip_bf16.h>

#define NRELS 8
#define NB 8
#define SCAN_B 1024

typedef __attribute__((ext_vector_type(8))) short short8v;
typedef __attribute__((ext_vector_type(4))) float f32x4;

__device__ __forceinline__ short bfc(float f) {
    __hip_bfloat16 h = __float2bfloat16(f);
    return *reinterpret_cast<short*>(&h);
}
__device__ __forceinline__ float bf2f(ushort u) {
    return __uint_as_float((unsigned)u << 16);
}
__device__ __forceinline__ short8v cvt8(float4 a, float4 b) {
    short8v r;
    r[0] = bfc(a.x); r[1] = bfc(a.y); r[2] = bfc(a.z); r[3] = bfc(a.w);
    r[4] = bfc(b.x); r[5] = bfc(b.y); r[6] = bfc(b.z); r[7] = bfc(b.w);
    return r;
}

// ---- W in MFMA B-frag order, even/odd column interleave (verified R5 layout).
// Y col = gg*32 + 2*(lane&15) + p ; frag f = gg*4 + p*2 + ks ; k = ks*32+(lane>>4)*8+j
__global__ void wprep_kernel(const float* __restrict__ basis1, const float* __restrict__ comp1,
                             const float* __restrict__ basis2, const float* __restrict__ comp2,
                             short* __restrict__ Wf1, short* __restrict__ Wf2) {
    int idx = blockIdx.x * blockDim.x + threadIdx.x;
    const int n1 = 64 * 512;
    const int n2 = 32 * 512;
    if (idx < n1) {
        int f = idx >> 9, lane = (idx >> 3) & 63, j = idx & 7;
        int ks = f & 1, p = (f >> 1) & 1, gg = f >> 2;
        int r = gg >> 1;
        int c = (gg & 1) * 32 + 2 * (lane & 15) + p;
        int k = ks * 32 + (lane >> 4) * 8 + j;
        float s = 0.f;
#pragma unroll
        for (int b = 0; b < NB; ++b)
            s = fmaf(comp1[r * NB + b], basis1[b * 4096 + k * 64 + c], s);
        Wf1[idx] = bfc(s);
    } else if (idx < n1 + n2) {
        int i2 = idx - n1;
        int f = i2 >> 9, lane = (i2 >> 3) & 63, j = i2 & 7;
        int ks = f & 1, p = (f >> 1) & 1, gg = f >> 2;
        int r = gg;
        int c = 2 * (lane & 15) + p;
        int k = ks * 32 + (lane >> 4) * 8 + j;
        float s = 0.f;
#pragma unroll
        for (int b = 0; b < NB; ++b)
            s = fmaf(comp2[r * NB + b], basis2[b * 2048 + k * 32 + c], s);
        Wf2[i2] = bfc(s);
    }
}

// ---- counting sort by dst (CSR end-offsets reused by edge kernels) ----
__global__ void hist2_kernel(const int* __restrict__ dst, int* __restrict__ cnt, int n) {
    for (int i = blockIdx.x * blockDim.x + threadIdx.x; i < n;
         i += gridDim.x * blockDim.x)
        atomicAdd(&cnt[dst[i]], 1);
}

__global__ void scan1_kernel(const int* __restrict__ cnt, int* __restrict__ part, int n) {
    __shared__ int sh[SCAN_B];
    int i = blockIdx.x * SCAN_B + threadIdx.x;
    sh[threadIdx.x] = (i < n) ? cnt[i] : 0;
    __syncthreads();
    for (int s = SCAN_B / 2; s > 0; s >>= 1) {
        if (threadIdx.x < s) sh[threadIdx.x] += sh[threadIdx.x + s];
        __syncthreads();
    }
    if (threadIdx.x == 0) part[blockIdx.x] = sh[0];
}

__global__ void scan2_kernel(int* __restrict__ part, int nb) {
    __shared__ int sh[256];
    int v = (threadIdx.x < nb) ? part[threadIdx.x] : 0;
    sh[threadIdx.x] = v;
    __syncthreads();
    for (int s = 1; s < 256; s <<= 1) {
        int t = (threadIdx.x >= s) ? sh[threadIdx.x - s] : 0;
        __syncthreads();
        sh[threadIdx.x] += t;
        __syncthreads();
    }
    if (threadIdx.x < nb) part[threadIdx.x] = sh[threadIdx.x] - v;   // exclusive
}

__global__ void scan3_kernel(const int* __restrict__ cnt, const int* __restrict__ part,
                             int* __restrict__ run, int n) {
    __shared__ int sh[SCAN_B];
    int i = blockIdx.x * SCAN_B + threadIdx.x;
    int v = (i < n) ? cnt[i] : 0;
    sh[threadIdx.x] = v;
    __syncthreads();
    for (int s = 1; s < SCAN_B; s <<= 1) {
        int t = (threadIdx.x >= s) ? sh[threadIdx.x - s] : 0;
        __syncthreads();
        sh[threadIdx.x] += t;
        __syncthreads();
    }
    if (i < n) run[i] = part[blockIdx.x] + sh[threadIdx.x] - v;
}

// packed meta: 8B per edge = (src | etype<<18, norm). dst implied by position (CSR).
__global__ void scatter2_kernel(const int* __restrict__ src, const int* __restrict__ dst,
                                const int* __restrict__ et, const float* __restrict__ norm,
                                int* __restrict__ run, uint2* __restrict__ meta, int n) {
    for (int i = blockIdx.x * blockDim.x + threadIdx.x; i < n;
         i += gridDim.x * blockDim.x) {
        int d = dst[i];
        int p = atomicAdd(&run[d], 1);
        meta[p] = make_uint2((unsigned)src[i] | ((unsigned)et[i] << 18),
                             (unsigned)__float_as_int(norm[i]));
    }
}

// ---- dense transform: Y[n, gg*32 + 2*ml + p] = X[n,:] @ W (bf16 packed-dword stores)
template <int G, bool BF16IN>
__global__ __launch_bounds__(256) void transform_kernel(
    const void* __restrict__ xin, const short* __restrict__ Wf,
    ushort* __restrict__ yb, int nNodes) {
    constexpr int TOUT = G * 32;
    const int lane = threadIdx.x & 63;
    const int wid = (blockIdx.x * blockDim.x + threadIdx.x) >> 6;
    const int base = wid * 64;
    if (base >= nNodes) return;
    const int ml = lane & 15, kg = lane >> 4;

    short8v A[4][2];
#pragma unroll
    for (int s = 0; s < 4; ++s) {
        int row = min(base + s * 16 + ml, nNodes - 1);
        if (BF16IN) {
            const ushort* xp = (const ushort*)xin + (size_t)row * 64 + kg * 8;
            A[s][0] = *(const short8v*)xp;
            A[s][1] = *(const short8v*)(xp + 32);
        } else {
            const float* xp = (const float*)xin + (size_t)row * 64 + kg * 8;
            float4 f0 = *(const float4*)xp;
            float4 f1 = *(const float4*)(xp + 4);
            float4 f2 = *(const float4*)(xp + 32);
            float4 f3 = *(const float4*)(xp + 36);
            A[s][0] = cvt8(f0, f1);
            A[s][1] = cvt8(f2, f3);
        }
    }
#pragma unroll
    for (int gg = 0; gg < G; ++gg) {
        const short* wp = Wf + (size_t)gg * 4 * 512 + lane * 8;
        short8v Be0 = *(const short8v*)(wp);
        short8v Be1 = *(const short8v*)(wp + 512);
        short8v Bo0 = *(const short8v*)(wp + 1024);
        short8v Bo1 = *(const short8v*)(wp + 1536);
#pragma unroll
        for (int s = 0; s < 4; ++s) {
            f32x4 ae = __builtin_amdgcn_mfma_f32_16x16x32_bf16(A[s][0], Be0,
                                                               (f32x4){0.f, 0.f, 0.f, 0.f}, 0, 0, 0);
            ae = __builtin_amdgcn_mfma_f32_16x16x32_bf16(A[s][1], Be1, ae, 0, 0, 0);
            f32x4 ao = __builtin_amdgcn_mfma_f32_16x16x32_bf16(A[s][0], Bo0,
                                                               (f32x4){0.f, 0.f, 0.f, 0.f}, 0, 0, 0);
            ao = __builtin_amdgcn_mfma_f32_16x16x32_bf16(A[s][1], Bo1, ao, 0, 0, 0);
#pragma unroll
            for (int i = 0; i < 4; ++i) {
                int row = base + s * 16 + kg * 4 + i;
                if (row < nNodes) {
                    unsigned pk = (unsigned)(ushort)bfc(ae[i]) |
                                  ((unsigned)(ushort)bfc(ao[i]) << 16);
                    *reinterpret_cast<unsigned*>(yb + (size_t)row * TOUT + gg * 32 + ml * 2) = pk;
                }
            }
        }
    }
}

// ---- edge aggregation: dst-RANGE partitioned groups -> zero atomics, no init.
// Group owns dsts [d0,d1); walks its CSR edge span; flushes each dst row exactly
// once (bias for empty rows). OutT=ushort(bf16) for h1, float for final out.
template <int OUT, typename OutT, bool ACCUM>
__global__ __launch_bounds__(256) void edge_kernel(
    const ushort* __restrict__ yb, const uint2* __restrict__ meta,
    const int* __restrict__ endOff, const float* __restrict__ bias,
    OutT* __restrict__ out, int nNodes, int D, int rtLo, int rtCnt, int rowStride) {
    const int lane = threadIdx.x & 63;
    constexpr int GPW = 64 / OUT;
    const int wid = (blockIdx.x * blockDim.x + threadIdx.x) >> 6;
    const int gid = wid * GPW + ((GPW == 2) ? (lane >> 5) : 0);
    const int o = lane & (OUT - 1);
    const int d0 = gid * D;
    if (d0 >= nNodes) return;
    const int d1 = min(d0 + D, nNodes);
    const float bv = bias[o];

    int e = (d0 == 0) ? 0 : endOff[d0 - 1];
    const int eEnd = endOff[d1 - 1];
    int dcur = d0;
    int bnd = endOff[dcur];
    float acc = 0.f;

    auto flush = [&](int d, float a) {
        size_t idx = (size_t)d * OUT + o;
        if (ACCUM) {
            out[idx] = (OutT)(ushort)bfc(bf2f((ushort)out[idx]) + a);
        } else if (sizeof(OutT) == 2) {
            out[idx] = (OutT)(ushort)bfc(bv + a);
        } else {
            out[idx] = (OutT)(bv + a);
        }
    };
    auto gather = [&](uint2 mm) -> float {
        int rr = (int)(mm.x >> 18) - rtLo;
        float v = 0.f;
        if ((unsigned)rr < (unsigned)rtCnt)
            v = bf2f(yb[(size_t)(mm.x & 0x3FFFFu) * rowStride + rr * OUT + o]);
        return v;
    };

    if (e < eEnd) {
        int eB = min(e + 1, eEnd - 1), eC = min(e + 2, eEnd - 1);
        uint2 M0 = meta[e], M1 = meta[eB], M2 = meta[eC];
        float V0 = gather(M0), V1 = gather(M1);
        for (; e < eEnd; ++e) {
            uint2 M3 = meta[min(e + 3, eEnd - 1)];
            float V2 = gather(M2);
            while (e >= bnd) {            // flush finished dsts (incl. empty runs)
                flush(dcur, acc);
                acc = 0.f;
                ++dcur;
                bnd = endOff[dcur];
            }
            acc = fmaf(__uint_as_float(M0.y), V0, acc);
            M0 = M1; M1 = M2; M2 = M3;
            V0 = V1; V1 = V2;
        }
    }
    for (; dcur < d1; ++dcur) { flush(dcur, acc); acc = 0.f; }
}

extern "C" void kernel_launch(void* const* d_in, const int* in_sizes, int n_in,
                              void* d_out, int out_size, void* d_ws, size_t ws_size,
                              hipStream_t stream) {
    const float* emb    = (const float*)d_in[0];
    const float* basis1 = (const float*)d_in[1];
    const float* comp1  = (const float*)d_in[2];
    const float* bias1  = (const float*)d_in[3];
    const float* basis2 = (const float*)d_in[4];
    const float* comp2  = (const float*)d_in[5];
    const float* bias2  = (const float*)d_in[6];
    const int*   src    = (const int*)d_in[7];
    const int*   dst    = (const int*)d_in[8];
    const int*   etype  = (const int*)d_in[9];
    const float* norm   = (const float*)d_in[10];
    float* out = (float*)d_out;

    const int nNodes = in_sizes[0] / 64;   // 200000
    const int nEdges = in_sizes[7];        // 1000000

    const int nBins = ((nNodes + SCAN_B - 1) / SCAN_B) * SCAN_B;
    const int nScanBlocks = nBins / SCAN_B;

    char* ws = (char*)d_ws;
    short* Wf1  = (short*)(ws);                      // 64 KB
    short* Wf2  = (short*)(ws + 65536);              // 32 KB
    int*   part = (int*)(ws + 98304);                // 1 KB
    int*   cnt2 = (int*)(ws + 102400);               // ~803 KB (becomes CSR end-offsets)
    size_t offMeta = 1048576;
    uint2* meta = (uint2*)(ws + offMeta);            // 8 MB
    size_t offY = offMeta + (((size_t)nEdges * 8 + 255) & ~(size_t)255);

    const size_t yFused = (size_t)nNodes * 512 * 2;  // 204.8 MB
    const size_t yHalf  = (size_t)nNodes * 256 * 2;  // 102.4 MB
    const size_t h1Sz   = (size_t)nNodes * 64 * 2;   // 25.6 MB
    const bool fused = ws_size >= offY + yFused + h1Sz;
    const size_t ySz = fused ? yFused : yHalf;
    ushort* yB  = (ushort*)(ws + offY);
    ushort* h1b = (ushort*)(ws + offY + ySz);

    hipMemsetAsync(cnt2, 0, (size_t)nBins * 4, stream);

    wprep_kernel<<<192, 256, 0, stream>>>(basis1, comp1, basis2, comp2, Wf1, Wf2);
    hist2_kernel<<<1024, 256, 0, stream>>>(dst, cnt2, nEdges);
    scan1_kernel<<<nScanBlocks, SCAN_B, 0, stream>>>(cnt2, part, nBins);
    scan2_kernel<<<1, 256, 0, stream>>>(part, nScanBlocks);
    scan3_kernel<<<nScanBlocks, SCAN_B, 0, stream>>>(cnt2, part, cnt2, nBins);
    scatter2_kernel<<<1024, 256, 0, stream>>>(src, dst, etype, norm, cnt2, meta, nEdges);
    // cnt2 now holds CSR end-offsets per dst.

    const int tBlocks = (((nNodes + 63) / 64) + 3) / 4;
    const int D = 13;                                  // dsts per group
    const int nGroups = (nNodes + D - 1) / D;
    const int b64 = (nGroups + 3) / 4;
    const int b32 = (nGroups + 7) / 8;

    if (fused) {
        transform_kernel<16, false><<<tBlocks, 256, 0, stream>>>(emb, Wf1, yB, nNodes);
        edge_kernel<64, ushort, false><<<b64, 256, 0, stream>>>(
            yB, meta, cnt2, bias1, h1b, nNodes, D, 0, 8, 512);
    } else {
        transform_kernel<8, false><<<tBlocks, 256, 0, stream>>>(emb, Wf1, yB, nNodes);
        edge_kernel<64, ushort, false><<<b64, 256, 0, stream>>>(
            yB, meta, cnt2, bias1, h1b, nNodes, D, 0, 4, 256);
        transform_kernel<8, false><<<tBlocks, 256, 0, stream>>>(emb, Wf1 + 16384, yB, nNodes);
        edge_kernel<64, ushort, true><<<b64, 256, 0, stream>>>(
            yB, meta, cnt2, bias1, h1b, nNodes, D, 4, 4, 256);
    }
    // ---- layer 2 ----
    transform_kernel<8, true><<<tBlocks, 256, 0, stream>>>(h1b, Wf2, yB, nNodes);
    edge_kernel<32, float, false><<<b32, 256, 0, stream>>>(
        yB, meta, cnt2, bias2, out, nNodes, D, 0, 8, 256);
}

// Round 7
// 330.628 us; speedup vs baseline: 3.0198x; 1.0517x over previous
//
#include <hip/hip_runtime.h>
#include <hip/hip_bf16.h>

#define NRELS 8
#define NB 8
#define SCAN_B 1024

typedef __attribute__((ext_vector_type(8))) short short8v;
typedef __attribute__((ext_vector_type(4))) float f32x4;

__device__ __forceinline__ short bfc(float f) {
    __hip_bfloat16 h = __float2bfloat16(f);
    return *reinterpret_cast<short*>(&h);
}
__device__ __forceinline__ float bf2f(ushort u) {
    return __uint_as_float((unsigned)u << 16);
}
__device__ __forceinline__ short8v cvt8(float4 a, float4 b) {
    short8v r;
    r[0] = bfc(a.x); r[1] = bfc(a.y); r[2] = bfc(a.z); r[3] = bfc(a.w);
    r[4] = bfc(b.x); r[5] = bfc(b.y); r[6] = bfc(b.z); r[7] = bfc(b.w);
    return r;
}

// ---- W in MFMA B-frag order, even/odd column interleave (verified R5/R6 layout).
__global__ void wprep_kernel(const float* __restrict__ basis1, const float* __restrict__ comp1,
                             const float* __restrict__ basis2, const float* __restrict__ comp2,
                             short* __restrict__ Wf1, short* __restrict__ Wf2) {
    int idx = blockIdx.x * blockDim.x + threadIdx.x;
    const int n1 = 64 * 512;
    const int n2 = 32 * 512;
    if (idx < n1) {
        int f = idx >> 9, lane = (idx >> 3) & 63, j = idx & 7;
        int ks = f & 1, p = (f >> 1) & 1, gg = f >> 2;
        int r = gg >> 1;
        int c = (gg & 1) * 32 + 2 * (lane & 15) + p;
        int k = ks * 32 + (lane >> 4) * 8 + j;
        float s = 0.f;
#pragma unroll
        for (int b = 0; b < NB; ++b)
            s = fmaf(comp1[r * NB + b], basis1[b * 4096 + k * 64 + c], s);
        Wf1[idx] = bfc(s);
    } else if (idx < n1 + n2) {
        int i2 = idx - n1;
        int f = i2 >> 9, lane = (i2 >> 3) & 63, j = i2 & 7;
        int ks = f & 1, p = (f >> 1) & 1, gg = f >> 2;
        int r = gg;
        int c = 2 * (lane & 15) + p;
        int k = ks * 32 + (lane >> 4) * 8 + j;
        float s = 0.f;
#pragma unroll
        for (int b = 0; b < NB; ++b)
            s = fmaf(comp2[r * NB + b], basis2[b * 2048 + k * 32 + c], s);
        Wf2[i2] = bfc(s);
    }
}

// ---- counting sort by dst (CSR end-offsets reused by edge kernels) ----
__global__ void hist2_kernel(const int* __restrict__ dst, int* __restrict__ cnt, int n) {
    for (int i = blockIdx.x * blockDim.x + threadIdx.x; i < n;
         i += gridDim.x * blockDim.x)
        atomicAdd(&cnt[dst[i]], 1);
}

__global__ void scan1_kernel(const int* __restrict__ cnt, int* __restrict__ part, int n) {
    __shared__ int sh[SCAN_B];
    int i = blockIdx.x * SCAN_B + threadIdx.x;
    sh[threadIdx.x] = (i < n) ? cnt[i] : 0;
    __syncthreads();
    for (int s = SCAN_B / 2; s > 0; s >>= 1) {
        if (threadIdx.x < s) sh[threadIdx.x] += sh[threadIdx.x + s];
        __syncthreads();
    }
    if (threadIdx.x == 0) part[blockIdx.x] = sh[0];
}

__global__ void scan2_kernel(int* __restrict__ part, int nb) {
    __shared__ int sh[256];
    int v = (threadIdx.x < nb) ? part[threadIdx.x] : 0;
    sh[threadIdx.x] = v;
    __syncthreads();
    for (int s = 1; s < 256; s <<= 1) {
        int t = (threadIdx.x >= s) ? sh[threadIdx.x - s] : 0;
        __syncthreads();
        sh[threadIdx.x] += t;
        __syncthreads();
    }
    if (threadIdx.x < nb) part[threadIdx.x] = sh[threadIdx.x] - v;   // exclusive
}

__global__ void scan3_kernel(const int* __restrict__ cnt, const int* __restrict__ part,
                             int* __restrict__ run, int n) {
    __shared__ int sh[SCAN_B];
    int i = blockIdx.x * SCAN_B + threadIdx.x;
    int v = (i < n) ? cnt[i] : 0;
    sh[threadIdx.x] = v;
    __syncthreads();
    for (int s = 1; s < SCAN_B; s <<= 1) {
        int t = (threadIdx.x >= s) ? sh[threadIdx.x - s] : 0;
        __syncthreads();
        sh[threadIdx.x] += t;
        __syncthreads();
    }
    if (i < n) run[i] = part[blockIdx.x] + sh[threadIdx.x] - v;
}

// packed meta: 8B/edge = (key = src*8 + etype, norm). dst implied by CSR position.
__global__ void scatter2_kernel(const int* __restrict__ src, const int* __restrict__ dst,
                                const int* __restrict__ et, const float* __restrict__ norm,
                                int* __restrict__ run, uint2* __restrict__ meta, int n) {
    for (int i = blockIdx.x * blockDim.x + threadIdx.x; i < n;
         i += gridDim.x * blockDim.x) {
        int d = dst[i];
        int p = atomicAdd(&run[d], 1);
        meta[p] = make_uint2(((unsigned)src[i] << 3) | (unsigned)et[i],
                             (unsigned)__float_as_int(norm[i]));
    }
}

// ---- dense transform: Y[n, gg*32 + 2*ml + p] = X[n,:] @ W (bf16 packed-dword stores)
template <int G, bool BF16IN>
__global__ __launch_bounds__(256) void transform_kernel(
    const void* __restrict__ xin, const short* __restrict__ Wf,
    ushort* __restrict__ yb, int nNodes) {
    constexpr int TOUT = G * 32;
    const int lane = threadIdx.x & 63;
    const int wid = (blockIdx.x * blockDim.x + threadIdx.x) >> 6;
    const int base = wid * 64;
    if (base >= nNodes) return;
    const int ml = lane & 15, kg = lane >> 4;

    short8v A[4][2];
#pragma unroll
    for (int s = 0; s < 4; ++s) {
        int row = min(base + s * 16 + ml, nNodes - 1);
        if (BF16IN) {
            const ushort* xp = (const ushort*)xin + (size_t)row * 64 + kg * 8;
            A[s][0] = *(const short8v*)xp;
            A[s][1] = *(const short8v*)(xp + 32);
        } else {
            const float* xp = (const float*)xin + (size_t)row * 64 + kg * 8;
            float4 f0 = *(const float4*)xp;
            float4 f1 = *(const float4*)(xp + 4);
            float4 f2 = *(const float4*)(xp + 32);
            float4 f3 = *(const float4*)(xp + 36);
            A[s][0] = cvt8(f0, f1);
            A[s][1] = cvt8(f2, f3);
        }
    }
#pragma unroll
    for (int gg = 0; gg < G; ++gg) {
        const short* wp = Wf + (size_t)gg * 4 * 512 + lane * 8;
        short8v Be0 = *(const short8v*)(wp);
        short8v Be1 = *(const short8v*)(wp + 512);
        short8v Bo0 = *(const short8v*)(wp + 1024);
        short8v Bo1 = *(const short8v*)(wp + 1536);
#pragma unroll
        for (int s = 0; s < 4; ++s) {
            f32x4 ae = __builtin_amdgcn_mfma_f32_16x16x32_bf16(A[s][0], Be0,
                                                               (f32x4){0.f, 0.f, 0.f, 0.f}, 0, 0, 0);
            ae = __builtin_amdgcn_mfma_f32_16x16x32_bf16(A[s][1], Be1, ae, 0, 0, 0);
            f32x4 ao = __builtin_amdgcn_mfma_f32_16x16x32_bf16(A[s][0], Bo0,
                                                               (f32x4){0.f, 0.f, 0.f, 0.f}, 0, 0, 0);
            ao = __builtin_amdgcn_mfma_f32_16x16x32_bf16(A[s][1], Bo1, ao, 0, 0, 0);
#pragma unroll
            for (int i = 0; i < 4; ++i) {
                int row = base + s * 16 + kg * 4 + i;
                if (row < nNodes) {
                    unsigned pk = (unsigned)(ushort)bfc(ae[i]) |
                                  ((unsigned)(ushort)bfc(ao[i]) << 16);
                    *reinterpret_cast<unsigned*>(yb + (size_t)row * TOUT + gg * 32 + ml * 2) = pk;
                }
            }
        }
    }
}

// ---- edge aggregation: dst-range groups, zero atomics, 32-bit shift-add gather.
// SHIFT: Y byte-offset = (key<<SHIFT) + (o<<1). FILTER: fallback rel-windowed layout.
// Boundaries: lane o<D holds endOff[d0+o]; flush advance = one __shfl.
template <int OUT, typename OutT, bool ACCUM, bool FILTER, int SHIFT>
__global__ __launch_bounds__(256) void edge_kernel(
    const ushort* __restrict__ yb, const uint2* __restrict__ meta,
    const int* __restrict__ endOff, const float* __restrict__ bias,
    OutT* __restrict__ out, int nNodes, int D, int rtLo) {
    const int lane = threadIdx.x & 63;
    constexpr int GPW = 64 / OUT;
    const int wid = (blockIdx.x * blockDim.x + threadIdx.x) >> 6;
    const int sub = (GPW == 2) ? (lane >> 5) : 0;
    const int gbase = sub << 5;
    const int gid = wid * GPW + sub;
    const int o = lane & (OUT - 1);
    const int d0 = gid * D;
    if (d0 >= nNodes) return;
    const int d1 = min(d0 + D, nNodes);
    const float bv = bias[o];

    int bndv = 0x7fffffff;
    if (o < D) bndv = endOff[min(d0 + o, nNodes - 1)];
    const int eEnd = __shfl(bndv, gbase + (d1 - 1 - d0));
    int e = (d0 == 0) ? 0 : endOff[d0 - 1];
    int dcur = d0;
    int bnd = __shfl(bndv, gbase);
    float acc = 0.f;

    auto gv = [&](unsigned key) -> float {
        if (FILTER) {
            int rr = (int)(key & 7u) - rtLo;
            if ((unsigned)rr >= 4u) return 0.f;
            unsigned off = (((key >> 3) * (unsigned)(4 * OUT)) +
                            (unsigned)rr * OUT + (unsigned)o) << 1;
            return bf2f(*(const ushort*)((const char*)yb + off));
        } else {
            unsigned off = (key << SHIFT) + ((unsigned)o << 1);
            return bf2f(*(const ushort*)((const char*)yb + off));
        }
    };
    auto flush = [&](int d, float a) {
        size_t idx = (size_t)d * OUT + o;
        if constexpr (ACCUM) {
            out[idx] = (OutT)(ushort)bfc(bf2f((ushort)out[idx]) + a);
        } else if constexpr (sizeof(OutT) == 2) {
            out[idx] = (OutT)(ushort)bfc(bv + a);
        } else {
            out[idx] = (OutT)(bv + a);
        }
    };

    if (e < eEnd) {
        const int eL = eEnd - 1;
        uint2 M0 = meta[e];
        uint2 M1 = meta[min(e + 1, eL)];
        uint2 M2 = meta[min(e + 2, eL)];
        float V0 = gv(M0.x);
        float V1 = gv(M1.x);
#pragma unroll 4
        for (; e < eEnd; ++e) {
            uint2 M3 = meta[min(e + 3, eL)];
            float V2 = gv(M2.x);
            while (e >= bnd) {
                flush(dcur, acc);
                acc = 0.f;
                ++dcur;
                bnd = __shfl(bndv, gbase + (dcur - d0));
            }
            acc = fmaf(__uint_as_float(M0.y), V0, acc);
            M0 = M1; M1 = M2; M2 = M3;
            V0 = V1; V1 = V2;
        }
    }
    for (; dcur < d1; ++dcur) {
        flush(dcur, acc);
        acc = 0.f;
    }
}

extern "C" void kernel_launch(void* const* d_in, const int* in_sizes, int n_in,
                              void* d_out, int out_size, void* d_ws, size_t ws_size,
                              hipStream_t stream) {
    const float* emb    = (const float*)d_in[0];
    const float* basis1 = (const float*)d_in[1];
    const float* comp1  = (const float*)d_in[2];
    const float* bias1  = (const float*)d_in[3];
    const float* basis2 = (const float*)d_in[4];
    const float* comp2  = (const float*)d_in[5];
    const float* bias2  = (const float*)d_in[6];
    const int*   src    = (const int*)d_in[7];
    const int*   dst    = (const int*)d_in[8];
    const int*   etype  = (const int*)d_in[9];
    const float* norm   = (const float*)d_in[10];
    float* out = (float*)d_out;

    const int nNodes = in_sizes[0] / 64;   // 200000
    const int nEdges = in_sizes[7];        // 1000000

    const int nBins = ((nNodes + SCAN_B - 1) / SCAN_B) * SCAN_B;
    const int nScanBlocks = nBins / SCAN_B;

    char* ws = (char*)d_ws;
    short* Wf1  = (short*)(ws);                      // 64 KB
    short* Wf2  = (short*)(ws + 65536);              // 32 KB
    int*   part = (int*)(ws + 98304);                // 1 KB
    int*   cnt2 = (int*)(ws + 102400);               // ~803 KB (becomes CSR end-offsets)
    size_t offMeta = 1048576;
    uint2* meta = (uint2*)(ws + offMeta);            // 8 MB
    size_t offY = offMeta + (((size_t)nEdges * 8 + 255) & ~(size_t)255);

    const size_t yFused = (size_t)nNodes * 512 * 2;  // 204.8 MB
    const size_t yHalf  = (size_t)nNodes * 256 * 2;  // 102.4 MB
    const size_t h1Sz   = (size_t)nNodes * 64 * 2;   // 25.6 MB
    const bool fused = ws_size >= offY + yFused + h1Sz;
    const size_t ySz = fused ? yFused : yHalf;
    ushort* yB  = (ushort*)(ws + offY);
    ushort* h1b = (ushort*)(ws + offY + ySz);

    hipMemsetAsync(cnt2, 0, (size_t)nBins * 4, stream);

    wprep_kernel<<<192, 256, 0, stream>>>(basis1, comp1, basis2, comp2, Wf1, Wf2);
    hist2_kernel<<<1024, 256, 0, stream>>>(dst, cnt2, nEdges);
    scan1_kernel<<<nScanBlocks, SCAN_B, 0, stream>>>(cnt2, part, nBins);
    scan2_kernel<<<1, 256, 0, stream>>>(part, nScanBlocks);
    scan3_kernel<<<nScanBlocks, SCAN_B, 0, stream>>>(cnt2, part, cnt2, nBins);
    scatter2_kernel<<<1024, 256, 0, stream>>>(src, dst, etype, norm, cnt2, meta, nEdges);
    // cnt2 now holds CSR end-offsets per dst.

    const int tBlocks = (((nNodes + 63) / 64) + 3) / 4;
    const int D = 8;                                   // dsts per group
    const int nGroups = (nNodes + D - 1) / D;          // 25000
    const int b64 = (nGroups + 3) / 4;
    const int b32 = (nGroups + 7) / 8;

    if (fused) {
        transform_kernel<16, false><<<tBlocks, 256, 0, stream>>>(emb, Wf1, yB, nNodes);
        edge_kernel<64, ushort, false, false, 7><<<b64, 256, 0, stream>>>(
            yB, meta, cnt2, bias1, h1b, nNodes, D, 0);
    } else {
        transform_kernel<8, false><<<tBlocks, 256, 0, stream>>>(emb, Wf1, yB, nNodes);
        edge_kernel<64, ushort, false, true, 0><<<b64, 256, 0, stream>>>(
            yB, meta, cnt2, bias1, h1b, nNodes, D, 0);
        transform_kernel<8, false><<<tBlocks, 256, 0, stream>>>(emb, Wf1 + 16384, yB, nNodes);
        edge_kernel<64, ushort, true, true, 0><<<b64, 256, 0, stream>>>(
            yB, meta, cnt2, bias1, h1b, nNodes, D, 4);
    }
    // ---- layer 2 ----
    transform_kernel<8, true><<<tBlocks, 256, 0, stream>>>(h1b, Wf2, yB, nNodes);
    edge_kernel<32, float, false, false, 6><<<b32, 256, 0, stream>>>(
        yB, meta, cnt2, bias2, out, nNodes, D, 0);
}

// Round 8
// 303.484 us; speedup vs baseline: 3.2899x; 1.0894x over previous
//
#include <hip/hip_runtime.h>
#include <hip/hip_bf16.h>

#define NRELS 8
#define NB 8
#define SCAN_B 1024

typedef __attribute__((ext_vector_type(8))) short short8v;
typedef __attribute__((ext_vector_type(4))) float f32x4;

__device__ __forceinline__ short bfc(float f) {
    __hip_bfloat16 h = __float2bfloat16(f);
    return *reinterpret_cast<short*>(&h);
}
__device__ __forceinline__ float bf2f(ushort u) {
    return __uint_as_float((unsigned)u << 16);
}
__device__ __forceinline__ short8v cvt8(float4 a, float4 b) {
    short8v r;
    r[0] = bfc(a.x); r[1] = bfc(a.y); r[2] = bfc(a.z); r[3] = bfc(a.w);
    r[4] = bfc(b.x); r[5] = bfc(b.y); r[6] = bfc(b.z); r[7] = bfc(b.w);
    return r;
}

// ---- W in MFMA B-frag order, 8-consecutive-col-per-lane packing.
// Col c = gg*128 + 8*(lane&15) + q, q in [0,8). Frag f = gg*16 + q*2 + ks.
// Element j: k = ks*32 + (lane>>4)*8 + j. Y layout stays row-major (identical to R7).
__global__ void wprep_kernel(const float* __restrict__ basis1, const float* __restrict__ comp1,
                             const float* __restrict__ basis2, const float* __restrict__ comp2,
                             short* __restrict__ Wf1, short* __restrict__ Wf2) {
    int idx = blockIdx.x * blockDim.x + threadIdx.x;
    const int n1 = 64 * 512;   // 64 frags (4 gg) x 64 lanes x 8
    const int n2 = 32 * 512;   // 32 frags (2 gg)
    if (idx < n1) {
        int f = idx >> 9, lane = (idx >> 3) & 63, j = idx & 7;
        int ks = f & 1, q = (f >> 1) & 7, gg = f >> 4;
        int c = gg * 128 + 8 * (lane & 15) + q;     // 0..511
        int k = ks * 32 + (lane >> 4) * 8 + j;
        int r = c >> 6, crel = c & 63;
        float s = 0.f;
#pragma unroll
        for (int b = 0; b < NB; ++b)
            s = fmaf(comp1[r * NB + b], basis1[b * 4096 + k * 64 + crel], s);
        Wf1[idx] = bfc(s);
    } else if (idx < n1 + n2) {
        int i2 = idx - n1;
        int f = i2 >> 9, lane = (i2 >> 3) & 63, j = i2 & 7;
        int ks = f & 1, q = (f >> 1) & 7, gg = f >> 4;
        int c = gg * 128 + 8 * (lane & 15) + q;     // 0..255
        int k = ks * 32 + (lane >> 4) * 8 + j;
        int r = c >> 5, crel = c & 31;
        float s = 0.f;
#pragma unroll
        for (int b = 0; b < NB; ++b)
            s = fmaf(comp2[r * NB + b], basis2[b * 2048 + k * 32 + crel], s);
        Wf2[i2] = bfc(s);
    }
}

// ---- counting sort by dst (CSR end-offsets reused by edge kernels) ----
__global__ void hist2_kernel(const int* __restrict__ dst, int* __restrict__ cnt, int n) {
    int i = (blockIdx.x * blockDim.x + threadIdx.x) * 4;
    if (i + 3 < n) {
        int4 d4 = *(const int4*)(dst + i);
        atomicAdd(&cnt[d4.x], 1);
        atomicAdd(&cnt[d4.y], 1);
        atomicAdd(&cnt[d4.z], 1);
        atomicAdd(&cnt[d4.w], 1);
    } else {
        for (; i < n; ++i) atomicAdd(&cnt[dst[i]], 1);
    }
}

__global__ void scan1_kernel(const int* __restrict__ cnt, int* __restrict__ part, int n) {
    __shared__ int sh[SCAN_B];
    int i = blockIdx.x * SCAN_B + threadIdx.x;
    sh[threadIdx.x] = (i < n) ? cnt[i] : 0;
    __syncthreads();
    for (int s = SCAN_B / 2; s > 0; s >>= 1) {
        if (threadIdx.x < s) sh[threadIdx.x] += sh[threadIdx.x + s];
        __syncthreads();
    }
    if (threadIdx.x == 0) part[blockIdx.x] = sh[0];
}

__global__ void scan2_kernel(int* __restrict__ part, int nb) {
    __shared__ int sh[256];
    int v = (threadIdx.x < nb) ? part[threadIdx.x] : 0;
    sh[threadIdx.x] = v;
    __syncthreads();
    for (int s = 1; s < 256; s <<= 1) {
        int t = (threadIdx.x >= s) ? sh[threadIdx.x - s] : 0;
        __syncthreads();
        sh[threadIdx.x] += t;
        __syncthreads();
    }
    if (threadIdx.x < nb) part[threadIdx.x] = sh[threadIdx.x] - v;   // exclusive
}

__global__ void scan3_kernel(const int* __restrict__ cnt, const int* __restrict__ part,
                             int* __restrict__ run, int n) {
    __shared__ int sh[SCAN_B];
    int i = blockIdx.x * SCAN_B + threadIdx.x;
    int v = (i < n) ? cnt[i] : 0;
    sh[threadIdx.x] = v;
    __syncthreads();
    for (int s = 1; s < SCAN_B; s <<= 1) {
        int t = (threadIdx.x >= s) ? sh[threadIdx.x - s] : 0;
        __syncthreads();
        sh[threadIdx.x] += t;
        __syncthreads();
    }
    if (i < n) run[i] = part[blockIdx.x] + sh[threadIdx.x] - v;
}

// packed meta: 8B/edge = (key = src*8 + etype, norm). dst implied by CSR position.
// 4 edges/thread: 4 independent atomics in flight before the dependent stores.
__global__ void scatter2_kernel(const int* __restrict__ src, const int* __restrict__ dst,
                                const int* __restrict__ et, const float* __restrict__ norm,
                                int* __restrict__ run, uint2* __restrict__ meta, int n) {
    int i = (blockIdx.x * blockDim.x + threadIdx.x) * 4;
    if (i + 3 < n) {
        int4 s4 = *(const int4*)(src + i);
        int4 d4 = *(const int4*)(dst + i);
        int4 e4 = *(const int4*)(et + i);
        float4 n4 = *(const float4*)(norm + i);
        int p0 = atomicAdd(&run[d4.x], 1);
        int p1 = atomicAdd(&run[d4.y], 1);
        int p2 = atomicAdd(&run[d4.z], 1);
        int p3 = atomicAdd(&run[d4.w], 1);
        meta[p0] = make_uint2(((unsigned)s4.x << 3) | (unsigned)e4.x, __float_as_uint(n4.x));
        meta[p1] = make_uint2(((unsigned)s4.y << 3) | (unsigned)e4.y, __float_as_uint(n4.y));
        meta[p2] = make_uint2(((unsigned)s4.z << 3) | (unsigned)e4.z, __float_as_uint(n4.z));
        meta[p3] = make_uint2(((unsigned)s4.w << 3) | (unsigned)e4.w, __float_as_uint(n4.w));
    } else {
        for (; i < n; ++i) {
            int p = atomicAdd(&run[dst[i]], 1);
            meta[p] = make_uint2(((unsigned)src[i] << 3) | (unsigned)et[i],
                                 __float_as_uint(norm[i]));
        }
    }
}

// ---- dense transform: Y[row, gg*128 + 8*ml + q] via q-packed 16B full-line stores.
template <int G128, bool BF16IN>
__global__ __launch_bounds__(256) void transform_kernel(
    const void* __restrict__ xin, const short* __restrict__ Wf,
    ushort* __restrict__ yb, int nNodes) {
    constexpr int TOUT = G128 * 128;
    const int lane = threadIdx.x & 63;
    const int wid = (blockIdx.x * blockDim.x + threadIdx.x) >> 6;
    const int base = wid * 64;
    if (base >= nNodes) return;
    const int ml = lane & 15, kg = lane >> 4;

    short8v A[4][2];
#pragma unroll
    for (int s = 0; s < 4; ++s) {
        int row = min(base + s * 16 + ml, nNodes - 1);
        if (BF16IN) {
            const ushort* xp = (const ushort*)xin + (size_t)row * 64 + kg * 8;
            A[s][0] = *(const short8v*)xp;
            A[s][1] = *(const short8v*)(xp + 32);
        } else {
            const float* xp = (const float*)xin + (size_t)row * 64 + kg * 8;
            float4 f0 = *(const float4*)xp;
            float4 f1 = *(const float4*)(xp + 4);
            float4 f2 = *(const float4*)(xp + 32);
            float4 f3 = *(const float4*)(xp + 36);
            A[s][0] = cvt8(f0, f1);
            A[s][1] = cvt8(f2, f3);
        }
    }
#pragma unroll
    for (int gg = 0; gg < G128; ++gg) {
        const short* wp = Wf + (size_t)gg * 16 * 512 + lane * 8;
#pragma unroll
        for (int s = 0; s < 4; ++s) {
            f32x4 acc[8];
#pragma unroll
            for (int q = 0; q < 8; ++q) {
                short8v B0 = *(const short8v*)(wp + (q * 2 + 0) * 512);
                short8v B1 = *(const short8v*)(wp + (q * 2 + 1) * 512);
                acc[q] = __builtin_amdgcn_mfma_f32_16x16x32_bf16(A[s][0], B0,
                                                                 (f32x4){0.f, 0.f, 0.f, 0.f}, 0, 0, 0);
                acc[q] = __builtin_amdgcn_mfma_f32_16x16x32_bf16(A[s][1], B1, acc[q], 0, 0, 0);
            }
#pragma unroll
            for (int i = 0; i < 4; ++i) {
                int row = base + s * 16 + kg * 4 + i;
                if (row < nNodes) {
                    uint4 pk;
                    pk.x = (unsigned)(ushort)bfc(acc[0][i]) | ((unsigned)(ushort)bfc(acc[1][i]) << 16);
                    pk.y = (unsigned)(ushort)bfc(acc[2][i]) | ((unsigned)(ushort)bfc(acc[3][i]) << 16);
                    pk.z = (unsigned)(ushort)bfc(acc[4][i]) | ((unsigned)(ushort)bfc(acc[5][i]) << 16);
                    pk.w = (unsigned)(ushort)bfc(acc[6][i]) | ((unsigned)(ushort)bfc(acc[7][i]) << 16);
                    *reinterpret_cast<uint4*>(yb + (size_t)row * TOUT + gg * 128 + ml * 8) = pk;
                }
            }
        }
    }
}

// ---- edge aggregation: dst-range groups, zero atomics, 32-bit shift-add gather.
template <int OUT, typename OutT, bool ACCUM, bool FILTER, int SHIFT>
__global__ __launch_bounds__(256) void edge_kernel(
    const ushort* __restrict__ yb, const uint2* __restrict__ meta,
    const int* __restrict__ endOff, const float* __restrict__ bias,
    OutT* __restrict__ out, int nNodes, int D, int rtLo) {
    const int lane = threadIdx.x & 63;
    constexpr int GPW = 64 / OUT;
    const int wid = (blockIdx.x * blockDim.x + threadIdx.x) >> 6;
    const int sub = (GPW == 2) ? (lane >> 5) : 0;
    const int gbase = sub << 5;
    const int gid = wid * GPW + sub;
    const int o = lane & (OUT - 1);
    const int d0 = gid * D;
    if (d0 >= nNodes) return;
    const int d1 = min(d0 + D, nNodes);
    const float bv = bias[o];

    int bndv = 0x7fffffff;
    if (o < D) bndv = endOff[min(d0 + o, nNodes - 1)];
    const int eEnd = __shfl(bndv, gbase + (d1 - 1 - d0));
    int e = (d0 == 0) ? 0 : endOff[d0 - 1];
    int dcur = d0;
    int bnd = __shfl(bndv, gbase);
    float acc = 0.f;

    auto gv = [&](unsigned key) -> float {
        if (FILTER) {
            int rr = (int)(key & 7u) - rtLo;
            if ((unsigned)rr >= 4u) return 0.f;
            unsigned off = (((key >> 3) * (unsigned)(4 * OUT)) +
                            (unsigned)rr * OUT + (unsigned)o) << 1;
            return bf2f(*(const ushort*)((const char*)yb + off));
        } else {
            unsigned off = (key << SHIFT) + ((unsigned)o << 1);
            return bf2f(*(const ushort*)((const char*)yb + off));
        }
    };
    auto flush = [&](int d, float a) {
        size_t idx = (size_t)d * OUT + o;
        if constexpr (ACCUM) {
            out[idx] = (OutT)(ushort)bfc(bf2f((ushort)out[idx]) + a);
        } else if constexpr (sizeof(OutT) == 2) {
            out[idx] = (OutT)(ushort)bfc(bv + a);
        } else {
            out[idx] = (OutT)(bv + a);
        }
    };

    if (e < eEnd) {
        const int eL = eEnd - 1;
        uint2 M0 = meta[e];
        uint2 M1 = meta[min(e + 1, eL)];
        uint2 M2 = meta[min(e + 2, eL)];
        float V0 = gv(M0.x);
        float V1 = gv(M1.x);
#pragma unroll 4
        for (; e < eEnd; ++e) {
            uint2 M3 = meta[min(e + 3, eL)];
            float V2 = gv(M2.x);
            while (e >= bnd) {
                flush(dcur, acc);
                acc = 0.f;
                ++dcur;
                bnd = __shfl(bndv, gbase + (dcur - d0));
            }
            acc = fmaf(__uint_as_float(M0.y), V0, acc);
            M0 = M1; M1 = M2; M2 = M3;
            V0 = V1; V1 = V2;
        }
    }
    for (; dcur < d1; ++dcur) {
        flush(dcur, acc);
        acc = 0.f;
    }
}

extern "C" void kernel_launch(void* const* d_in, const int* in_sizes, int n_in,
                              void* d_out, int out_size, void* d_ws, size_t ws_size,
                              hipStream_t stream) {
    const float* emb    = (const float*)d_in[0];
    const float* basis1 = (const float*)d_in[1];
    const float* comp1  = (const float*)d_in[2];
    const float* bias1  = (const float*)d_in[3];
    const float* basis2 = (const float*)d_in[4];
    const float* comp2  = (const float*)d_in[5];
    const float* bias2  = (const float*)d_in[6];
    const int*   src    = (const int*)d_in[7];
    const int*   dst    = (const int*)d_in[8];
    const int*   etype  = (const int*)d_in[9];
    const float* norm   = (const float*)d_in[10];
    float* out = (float*)d_out;

    const int nNodes = in_sizes[0] / 64;   // 200000
    const int nEdges = in_sizes[7];        // 1000000

    const int nBins = ((nNodes + SCAN_B - 1) / SCAN_B) * SCAN_B;
    const int nScanBlocks = nBins / SCAN_B;

    char* ws = (char*)d_ws;
    short* Wf1  = (short*)(ws);                      // 64 KB
    short* Wf2  = (short*)(ws + 65536);              // 32 KB
    int*   part = (int*)(ws + 98304);                // 1 KB
    int*   cnt2 = (int*)(ws + 102400);               // ~803 KB (becomes CSR end-offsets)
    size_t offMeta = 1048576;
    uint2* meta = (uint2*)(ws + offMeta);            // 8 MB
    size_t offY = offMeta + (((size_t)nEdges * 8 + 255) & ~(size_t)255);

    const size_t yFused = (size_t)nNodes * 512 * 2;  // 204.8 MB
    const size_t yHalf  = (size_t)nNodes * 256 * 2;  // 102.4 MB
    const size_t h1Sz   = (size_t)nNodes * 64 * 2;   // 25.6 MB
    const bool fused = ws_size >= offY + yFused + h1Sz;
    const size_t ySz = fused ? yFused : yHalf;
    ushort* yB  = (ushort*)(ws + offY);
    ushort* h1b = (ushort*)(ws + offY + ySz);

    hipMemsetAsync(cnt2, 0, (size_t)nBins * 4, stream);

    wprep_kernel<<<192, 256, 0, stream>>>(basis1, comp1, basis2, comp2, Wf1, Wf2);
    const int qBlocks = ((nEdges + 3) / 4 + 255) / 256;   // 977
    hist2_kernel<<<qBlocks, 256, 0, stream>>>(dst, cnt2, nEdges);
    scan1_kernel<<<nScanBlocks, SCAN_B, 0, stream>>>(cnt2, part, nBins);
    scan2_kernel<<<1, 256, 0, stream>>>(part, nScanBlocks);
    scan3_kernel<<<nScanBlocks, SCAN_B, 0, stream>>>(cnt2, part, cnt2, nBins);
    scatter2_kernel<<<qBlocks, 256, 0, stream>>>(src, dst, etype, norm, cnt2, meta, nEdges);
    // cnt2 now holds CSR end-offsets per dst.

    const int tBlocks = (((nNodes + 63) / 64) + 3) / 4;
    const int D = 8;                                   // dsts per group
    const int nGroups = (nNodes + D - 1) / D;          // 25000
    const int b64 = (nGroups + 3) / 4;
    const int b32 = (nGroups + 7) / 8;

    if (fused) {
        transform_kernel<4, false><<<tBlocks, 256, 0, stream>>>(emb, Wf1, yB, nNodes);
        edge_kernel<64, ushort, false, false, 7><<<b64, 256, 0, stream>>>(
            yB, meta, cnt2, bias1, h1b, nNodes, D, 0);
    } else {
        transform_kernel<2, false><<<tBlocks, 256, 0, stream>>>(emb, Wf1, yB, nNodes);
        edge_kernel<64, ushort, false, true, 0><<<b64, 256, 0, stream>>>(
            yB, meta, cnt2, bias1, h1b, nNodes, D, 0);
        transform_kernel<2, false><<<tBlocks, 256, 0, stream>>>(emb, Wf1 + 16384, yB, nNodes);
        edge_kernel<64, ushort, true, true, 0><<<b64, 256, 0, stream>>>(
            yB, meta, cnt2, bias1, h1b, nNodes, D, 4);
    }
    // ---- layer 2 ----
    transform_kernel<2, true><<<tBlocks, 256, 0, stream>>>(h1b, Wf2, yB, nNodes);
    edge_kernel<32, float, false, false, 6><<<b32, 256, 0, stream>>>(
        yB, meta, cnt2, bias2, out, nNodes, D, 0);
}

// Round 9
// 289.825 us; speedup vs baseline: 3.4449x; 1.0471x over previous
//
#include <hip/hip_runtime.h>
#include <hip/hip_bf16.h>

#define NRELS 8
#define NB 8
#define PBLK 128          // partition blocks
#define BSH 9             // dsts per bucket = 512
#define BCAP 3584         // max edges per bucket staged in LDS (+20 sigma)

typedef __attribute__((ext_vector_type(8))) short short8v;
typedef __attribute__((ext_vector_type(4))) float f32x4;

__device__ __forceinline__ short bfc(float f) {
    __hip_bfloat16 h = __float2bfloat16(f);
    return *reinterpret_cast<short*>(&h);
}
__device__ __forceinline__ float bf2f(ushort u) {
    return __uint_as_float((unsigned)u << 16);
}
__device__ __forceinline__ short8v cvt8(float4 a, float4 b) {
    short8v r;
    r[0] = bfc(a.x); r[1] = bfc(a.y); r[2] = bfc(a.z); r[3] = bfc(a.w);
    r[4] = bfc(b.x); r[5] = bfc(b.y); r[6] = bfc(b.z); r[7] = bfc(b.w);
    return r;
}

// ---- W in MFMA B-frag order, 8-consecutive-col-per-lane packing (verified R8).
__global__ void wprep_kernel(const float* __restrict__ basis1, const float* __restrict__ comp1,
                             const float* __restrict__ basis2, const float* __restrict__ comp2,
                             short* __restrict__ Wf1, short* __restrict__ Wf2) {
    int idx = blockIdx.x * blockDim.x + threadIdx.x;
    const int n1 = 64 * 512;
    const int n2 = 32 * 512;
    if (idx < n1) {
        int f = idx >> 9, lane = (idx >> 3) & 63, j = idx & 7;
        int ks = f & 1, q = (f >> 1) & 7, gg = f >> 4;
        int c = gg * 128 + 8 * (lane & 15) + q;
        int k = ks * 32 + (lane >> 4) * 8 + j;
        int r = c >> 6, crel = c & 63;
        float s = 0.f;
#pragma unroll
        for (int b = 0; b < NB; ++b)
            s = fmaf(comp1[r * NB + b], basis1[b * 4096 + k * 64 + crel], s);
        Wf1[idx] = bfc(s);
    } else if (idx < n1 + n2) {
        int i2 = idx - n1;
        int f = i2 >> 9, lane = (i2 >> 3) & 63, j = i2 & 7;
        int ks = f & 1, q = (f >> 1) & 7, gg = f >> 4;
        int c = gg * 128 + 8 * (lane & 15) + q;
        int k = ks * 32 + (lane >> 4) * 8 + j;
        int r = c >> 5, crel = c & 31;
        float s = 0.f;
#pragma unroll
        for (int b = 0; b < NB; ++b)
            s = fmaf(comp2[r * NB + b], basis2[b * 2048 + k * 32 + crel], s);
        Wf2[i2] = bfc(s);
    }
}

// ---- sort stage 1: per-block coarse histogram (no global atomics) ----
__global__ void histA_kernel(const int* __restrict__ dst, int* __restrict__ histM,
                             int nEdges, int nBuck, int chunk) {
    __shared__ int h[512];
    for (int t = threadIdx.x; t < nBuck; t += 256) h[t] = 0;
    __syncthreads();
    int start = blockIdx.x * chunk;
    int end = min(nEdges, start + chunk);
    for (int i = start + threadIdx.x; i < end; i += 256)
        atomicAdd(&h[dst[i] >> BSH], 1);
    __syncthreads();
    for (int t = threadIdx.x; t < nBuck; t += 256)
        histM[blockIdx.x * nBuck + t] = h[t];
}

// ---- sort stage 2: column scan -> bucketBase + per-(block,bucket) offsets ----
__global__ void scanA_kernel(const int* __restrict__ histM, int* __restrict__ offs,
                             int* __restrict__ bucketBase, int nBuck, int nBlk, int nEdges) {
    __shared__ int tot[512];
    const int b = threadIdx.x;
    int s = 0;
    if (b < nBuck)
        for (int k = 0; k < nBlk; ++k) s += histM[k * nBuck + b];
    tot[b] = s;
    __syncthreads();
    int own = s;
    for (int st = 1; st < 512; st <<= 1) {
        int t = (b >= st) ? tot[b - st] : 0;
        __syncthreads();
        tot[b] += t;
        __syncthreads();
    }
    int base = tot[b] - own;   // exclusive
    if (b < nBuck) {
        bucketBase[b] = base;
        int run = base;
        for (int k = 0; k < nBlk; k += 4) {
            int v0 = histM[(k + 0) * nBuck + b];
            int v1 = histM[(k + 1) * nBuck + b];
            int v2 = histM[(k + 2) * nBuck + b];
            int v3 = histM[(k + 3) * nBuck + b];
            offs[(k + 0) * nBuck + b] = run; run += v0;
            offs[(k + 1) * nBuck + b] = run; run += v1;
            offs[(k + 2) * nBuck + b] = run; run += v2;
            offs[(k + 3) * nBuck + b] = run; run += v3;
        }
    }
    if (b == 0) bucketBase[nBuck] = nEdges;
}

// ---- sort stage 3: partition into coarse buckets, line-dense runs ----
// staged.x = dstlocal<<21 | src<<3 | etype ; staged.y = norm
__global__ void part_kernel(const int* __restrict__ src, const int* __restrict__ dst,
                            const int* __restrict__ et, const float* __restrict__ norm,
                            const int* __restrict__ offs, uint2* __restrict__ staged,
                            int nEdges, int nBuck, int chunk) {
    __shared__ int cur[512];
    for (int t = threadIdx.x; t < nBuck; t += 256)
        cur[t] = offs[blockIdx.x * nBuck + t];
    __syncthreads();
    int start = blockIdx.x * chunk;
    int end = min(nEdges, start + chunk);
    for (int i = start + threadIdx.x; i < end; i += 256) {
        int d = dst[i];
        int b = d >> BSH;
        int p = atomicAdd(&cur[b], 1);
        staged[p] = make_uint2(((unsigned)(d & 511) << 21) |
                               ((unsigned)src[i] << 3) | (unsigned)et[i],
                               __float_as_uint(norm[i]));
    }
}

// ---- sort stage 4: per-bucket exact sort in LDS; in-place meta rewrite + endOff ----
__global__ void sortB_kernel(uint2* __restrict__ meta, const int* __restrict__ bucketBase,
                             int* __restrict__ endOff, int nNodes) {
    const int b = blockIdx.x;
    const int tid = threadIdx.x;
    const int e0 = bucketBase[b];
    const int n = min(bucketBase[b + 1] - e0, BCAP);
    __shared__ uint2 st[BCAP];
    __shared__ int h[512];
    __shared__ int pb[256];
    h[2 * tid] = 0; h[2 * tid + 1] = 0;
    __syncthreads();
    for (int j = tid; j < n; j += 256) {
        uint2 v = meta[e0 + j];
        st[j] = v;
        atomicAdd(&h[v.x >> 21], 1);
    }
    __syncthreads();
    int h0 = h[2 * tid], h1v = h[2 * tid + 1];
    int ps = h0 + h1v;
    pb[tid] = ps;
    __syncthreads();
    for (int s = 1; s < 256; s <<= 1) {
        int t = (tid >= s) ? pb[tid - s] : 0;
        __syncthreads();
        pb[tid] += t;
        __syncthreads();
    }
    int ex = pb[tid] - ps;     // exclusive pair base
    int d0 = b << BSH;
    int dA = d0 + 2 * tid, dB = dA + 1;
    if (dA < nNodes) endOff[dA] = e0 + ex + h0;
    if (dB < nNodes) endOff[dB] = e0 + ex + ps;
    h[2 * tid] = ex;
    h[2 * tid + 1] = ex + h0;
    __syncthreads();
    for (int j = tid; j < n; j += 256) {
        uint2 v = st[j];
        int r = atomicAdd(&h[v.x >> 21], 1);
        meta[e0 + r] = make_uint2(v.x & 0x1FFFFFu, v.y);
    }
}

// ---- dense transform: Y[row, gg*128 + 8*ml + q] via 16B full-line stores (R8) ----
template <int G128, bool BF16IN>
__global__ __launch_bounds__(256) void transform_kernel(
    const void* __restrict__ xin, const short* __restrict__ Wf,
    ushort* __restrict__ yb, int nNodes) {
    constexpr int TOUT = G128 * 128;
    const int lane = threadIdx.x & 63;
    const int wid = (blockIdx.x * blockDim.x + threadIdx.x) >> 6;
    const int base = wid * 64;
    if (base >= nNodes) return;
    const int ml = lane & 15, kg = lane >> 4;

    short8v A[4][2];
#pragma unroll
    for (int s = 0; s < 4; ++s) {
        int row = min(base + s * 16 + ml, nNodes - 1);
        if (BF16IN) {
            const ushort* xp = (const ushort*)xin + (size_t)row * 64 + kg * 8;
            A[s][0] = *(const short8v*)xp;
            A[s][1] = *(const short8v*)(xp + 32);
        } else {
            const float* xp = (const float*)xin + (size_t)row * 64 + kg * 8;
            float4 f0 = *(const float4*)xp;
            float4 f1 = *(const float4*)(xp + 4);
            float4 f2 = *(const float4*)(xp + 32);
            float4 f3 = *(const float4*)(xp + 36);
            A[s][0] = cvt8(f0, f1);
            A[s][1] = cvt8(f2, f3);
        }
    }
#pragma unroll
    for (int gg = 0; gg < G128; ++gg) {
        const short* wp = Wf + (size_t)gg * 16 * 512 + lane * 8;
#pragma unroll
        for (int s = 0; s < 4; ++s) {
            f32x4 acc[8];
#pragma unroll
            for (int q = 0; q < 8; ++q) {
                short8v B0 = *(const short8v*)(wp + (q * 2 + 0) * 512);
                short8v B1 = *(const short8v*)(wp + (q * 2 + 1) * 512);
                acc[q] = __builtin_amdgcn_mfma_f32_16x16x32_bf16(A[s][0], B0,
                                                                 (f32x4){0.f, 0.f, 0.f, 0.f}, 0, 0, 0);
                acc[q] = __builtin_amdgcn_mfma_f32_16x16x32_bf16(A[s][1], B1, acc[q], 0, 0, 0);
            }
#pragma unroll
            for (int i = 0; i < 4; ++i) {
                int row = base + s * 16 + kg * 4 + i;
                if (row < nNodes) {
                    uint4 pk;
                    pk.x = (unsigned)(ushort)bfc(acc[0][i]) | ((unsigned)(ushort)bfc(acc[1][i]) << 16);
                    pk.y = (unsigned)(ushort)bfc(acc[2][i]) | ((unsigned)(ushort)bfc(acc[3][i]) << 16);
                    pk.z = (unsigned)(ushort)bfc(acc[4][i]) | ((unsigned)(ushort)bfc(acc[5][i]) << 16);
                    pk.w = (unsigned)(ushort)bfc(acc[6][i]) | ((unsigned)(ushort)bfc(acc[7][i]) << 16);
                    *reinterpret_cast<uint4*>(yb + (size_t)row * TOUT + gg * 128 + ml * 8) = pk;
                }
            }
        }
    }
}

// ---- edge aggregation: dst-range groups, zero atomics, shift-add gather (R8) ----
template <int OUT, typename OutT, bool ACCUM, bool FILTER, int SHIFT>
__global__ __launch_bounds__(256) void edge_kernel(
    const ushort* __restrict__ yb, const uint2* __restrict__ meta,
    const int* __restrict__ endOff, const float* __restrict__ bias,
    OutT* __restrict__ out, int nNodes, int D, int rtLo) {
    const int lane = threadIdx.x & 63;
    constexpr int GPW = 64 / OUT;
    const int wid = (blockIdx.x * blockDim.x + threadIdx.x) >> 6;
    const int sub = (GPW == 2) ? (lane >> 5) : 0;
    const int gbase = sub << 5;
    const int gid = wid * GPW + sub;
    const int o = lane & (OUT - 1);
    const int d0 = gid * D;
    if (d0 >= nNodes) return;
    const int d1 = min(d0 + D, nNodes);
    const float bv = bias[o];

    int bndv = 0x7fffffff;
    if (o < D) bndv = endOff[min(d0 + o, nNodes - 1)];
    const int eEnd = __shfl(bndv, gbase + (d1 - 1 - d0));
    int e = (d0 == 0) ? 0 : endOff[d0 - 1];
    int dcur = d0;
    int bnd = __shfl(bndv, gbase);
    float acc = 0.f;

    auto gv = [&](unsigned key) -> float {
        if (FILTER) {
            int rr = (int)(key & 7u) - rtLo;
            if ((unsigned)rr >= 4u) return 0.f;
            unsigned off = (((key >> 3) * (unsigned)(4 * OUT)) +
                            (unsigned)rr * OUT + (unsigned)o) << 1;
            return bf2f(*(const ushort*)((const char*)yb + off));
        } else {
            unsigned off = (key << SHIFT) + ((unsigned)o << 1);
            return bf2f(*(const ushort*)((const char*)yb + off));
        }
    };
    auto flush = [&](int d, float a) {
        size_t idx = (size_t)d * OUT + o;
        if constexpr (ACCUM) {
            out[idx] = (OutT)(ushort)bfc(bf2f((ushort)out[idx]) + a);
        } else if constexpr (sizeof(OutT) == 2) {
            out[idx] = (OutT)(ushort)bfc(bv + a);
        } else {
            out[idx] = (OutT)(bv + a);
        }
    };

    if (e < eEnd) {
        const int eL = eEnd - 1;
        uint2 M0 = meta[e];
        uint2 M1 = meta[min(e + 1, eL)];
        uint2 M2 = meta[min(e + 2, eL)];
        float V0 = gv(M0.x);
        float V1 = gv(M1.x);
#pragma unroll 4
        for (; e < eEnd; ++e) {
            uint2 M3 = meta[min(e + 3, eL)];
            float V2 = gv(M2.x);
            while (e >= bnd) {
                flush(dcur, acc);
                acc = 0.f;
                ++dcur;
                bnd = __shfl(bndv, gbase + (dcur - d0));
            }
            acc = fmaf(__uint_as_float(M0.y), V0, acc);
            M0 = M1; M1 = M2; M2 = M3;
            V0 = V1; V1 = V2;
        }
    }
    for (; dcur < d1; ++dcur) {
        flush(dcur, acc);
        acc = 0.f;
    }
}

extern "C" void kernel_launch(void* const* d_in, const int* in_sizes, int n_in,
                              void* d_out, int out_size, void* d_ws, size_t ws_size,
                              hipStream_t stream) {
    const float* emb    = (const float*)d_in[0];
    const float* basis1 = (const float*)d_in[1];
    const float* comp1  = (const float*)d_in[2];
    const float* bias1  = (const float*)d_in[3];
    const float* basis2 = (const float*)d_in[4];
    const float* comp2  = (const float*)d_in[5];
    const float* bias2  = (const float*)d_in[6];
    const int*   src    = (const int*)d_in[7];
    const int*   dst    = (const int*)d_in[8];
    const int*   etype  = (const int*)d_in[9];
    const float* norm   = (const float*)d_in[10];
    float* out = (float*)d_out;

    const int nNodes = in_sizes[0] / 64;   // 200000
    const int nEdges = in_sizes[7];        // 1000000

    const int nBuck = (nNodes + 511) >> BSH;            // 391
    const int chunk = (nEdges + PBLK - 1) / PBLK;       // 7813

    char* ws = (char*)d_ws;
    short* Wf1        = (short*)(ws);                               // 64 KB
    short* Wf2        = (short*)(ws + 65536);                       // 32 KB
    int*   histM      = (int*)(ws + 98304);                         // 200,192 B
    int*   offs       = (int*)(ws + 298496);                        // 200,192 B
    int*   bucketBase = (int*)(ws + 498688);                        // 1,568 B
    int*   endOff     = (int*)(ws + 500480);                        // 800,000 B
    size_t offMeta = 1300480;
    uint2* meta       = (uint2*)(ws + offMeta);                     // 8 MB
    size_t offY = offMeta + (size_t)nEdges * 8;

    const size_t yFused = (size_t)nNodes * 512 * 2;  // 204.8 MB
    const size_t yHalf  = (size_t)nNodes * 256 * 2;  // 102.4 MB
    const size_t h1Sz   = (size_t)nNodes * 64 * 2;   // 25.6 MB
    const bool fused = ws_size >= offY + yFused + h1Sz;
    const size_t ySz = fused ? yFused : yHalf;
    ushort* yB  = (ushort*)(ws + offY);
    ushort* h1b = (ushort*)(ws + offY + ySz);

    // ---- sort (no global atomics, line-dense writes) ----
    wprep_kernel<<<192, 256, 0, stream>>>(basis1, comp1, basis2, comp2, Wf1, Wf2);
    histA_kernel<<<PBLK, 256, 0, stream>>>(dst, histM, nEdges, nBuck, chunk);
    scanA_kernel<<<1, 512, 0, stream>>>(histM, offs, bucketBase, nBuck, PBLK, nEdges);
    part_kernel<<<PBLK, 256, 0, stream>>>(src, dst, etype, norm, offs, meta,
                                          nEdges, nBuck, chunk);
    sortB_kernel<<<nBuck, 256, 0, stream>>>(meta, bucketBase, endOff, nNodes);

    const int tBlocks = (((nNodes + 63) / 64) + 3) / 4;
    const int D = 8;
    const int nGroups = (nNodes + D - 1) / D;
    const int b64 = (nGroups + 3) / 4;
    const int b32 = (nGroups + 7) / 8;

    if (fused) {
        transform_kernel<4, false><<<tBlocks, 256, 0, stream>>>(emb, Wf1, yB, nNodes);
        edge_kernel<64, ushort, false, false, 7><<<b64, 256, 0, stream>>>(
            yB, meta, endOff, bias1, h1b, nNodes, D, 0);
    } else {
        transform_kernel<2, false><<<tBlocks, 256, 0, stream>>>(emb, Wf1, yB, nNodes);
        edge_kernel<64, ushort, false, true, 0><<<b64, 256, 0, stream>>>(
            yB, meta, endOff, bias1, h1b, nNodes, D, 0);
        transform_kernel<2, false><<<tBlocks, 256, 0, stream>>>(emb, Wf1 + 16384, yB, nNodes);
        edge_kernel<64, ushort, true, true, 0><<<b64, 256, 0, stream>>>(
            yB, meta, endOff, bias1, h1b, nNodes, D, 4);
    }
    // ---- layer 2 ----
    transform_kernel<2, true><<<tBlocks, 256, 0, stream>>>(h1b, Wf2, yB, nNodes);
    edge_kernel<32, float, false, false, 6><<<b32, 256, 0, stream>>>(
        yB, meta, endOff, bias2, out, nNodes, D, 0);
}

// Round 10
// 266.998 us; speedup vs baseline: 3.7394x; 1.0855x over previous
//
#include <hip/hip_runtime.h>
#include <hip/hip_bf16.h>

#define NRELS 8
#define NB 8
#define PBLK 128          // partition blocks
#define BSH 9             // dsts per bucket = 512
#define BCAP 3584         // max edges per bucket staged in LDS

typedef __attribute__((ext_vector_type(8))) short short8v;
typedef __attribute__((ext_vector_type(4))) float f32x4;

__device__ __forceinline__ short bfc(float f) {
    __hip_bfloat16 h = __float2bfloat16(f);
    return *reinterpret_cast<short*>(&h);
}
__device__ __forceinline__ float bf2f(ushort u) {
    return __uint_as_float((unsigned)u << 16);
}
__device__ __forceinline__ short8v cvt8(float4 a, float4 b) {
    short8v r;
    r[0] = bfc(a.x); r[1] = bfc(a.y); r[2] = bfc(a.z); r[3] = bfc(a.w);
    r[4] = bfc(b.x); r[5] = bfc(b.y); r[6] = bfc(b.z); r[7] = bfc(b.w);
    return r;
}

// ---- W in MFMA B-frag order, 8-consecutive-col-per-lane packing (verified R8).
__global__ void wprep_kernel(const float* __restrict__ basis1, const float* __restrict__ comp1,
                             const float* __restrict__ basis2, const float* __restrict__ comp2,
                             short* __restrict__ Wf1, short* __restrict__ Wf2) {
    int idx = blockIdx.x * blockDim.x + threadIdx.x;
    const int n1 = 64 * 512;
    const int n2 = 32 * 512;
    if (idx < n1) {
        int f = idx >> 9, lane = (idx >> 3) & 63, j = idx & 7;
        int ks = f & 1, q = (f >> 1) & 7, gg = f >> 4;
        int c = gg * 128 + 8 * (lane & 15) + q;
        int k = ks * 32 + (lane >> 4) * 8 + j;
        int r = c >> 6, crel = c & 63;
        float s = 0.f;
#pragma unroll
        for (int b = 0; b < NB; ++b)
            s = fmaf(comp1[r * NB + b], basis1[b * 4096 + k * 64 + crel], s);
        Wf1[idx] = bfc(s);
    } else if (idx < n1 + n2) {
        int i2 = idx - n1;
        int f = i2 >> 9, lane = (i2 >> 3) & 63, j = i2 & 7;
        int ks = f & 1, q = (f >> 1) & 7, gg = f >> 4;
        int c = gg * 128 + 8 * (lane & 15) + q;
        int k = ks * 32 + (lane >> 4) * 8 + j;
        int r = c >> 5, crel = c & 31;
        float s = 0.f;
#pragma unroll
        for (int b = 0; b < NB; ++b)
            s = fmaf(comp2[r * NB + b], basis2[b * 2048 + k * 32 + crel], s);
        Wf2[i2] = bfc(s);
    }
}

// ---- sort stage 1: per-block coarse histogram (no global atomics) ----
__global__ void histA_kernel(const int* __restrict__ dst, int* __restrict__ histM,
                             int nEdges, int nBuck, int chunk) {
    __shared__ int h[512];
    for (int t = threadIdx.x; t < nBuck; t += 256) h[t] = 0;
    __syncthreads();
    int start = blockIdx.x * chunk;
    int end = min(nEdges, start + chunk);
    for (int i = start + threadIdx.x; i < end; i += 256)
        atomicAdd(&h[dst[i] >> BSH], 1);
    __syncthreads();
    for (int t = threadIdx.x; t < nBuck; t += 256)
        histM[blockIdx.x * nBuck + t] = h[t];
}

// ---- sort stage 2: column scan -> bucketBase + per-(block,bucket) offsets ----
__global__ void scanA_kernel(const int* __restrict__ histM, int* __restrict__ offs,
                             int* __restrict__ bucketBase, int nBuck, int nBlk, int nEdges) {
    __shared__ int tot[512];
    const int b = threadIdx.x;
    int s = 0;
    if (b < nBuck)
        for (int k = 0; k < nBlk; ++k) s += histM[k * nBuck + b];
    tot[b] = s;
    __syncthreads();
    int own = s;
    for (int st = 1; st < 512; st <<= 1) {
        int t = (b >= st) ? tot[b - st] : 0;
        __syncthreads();
        tot[b] += t;
        __syncthreads();
    }
    int base = tot[b] - own;   // exclusive
    if (b < nBuck) {
        bucketBase[b] = base;
        int run = base;
        for (int k = 0; k < nBlk; k += 4) {
            int v0 = histM[(k + 0) * nBuck + b];
            int v1 = histM[(k + 1) * nBuck + b];
            int v2 = histM[(k + 2) * nBuck + b];
            int v3 = histM[(k + 3) * nBuck + b];
            offs[(k + 0) * nBuck + b] = run; run += v0;
            offs[(k + 1) * nBuck + b] = run; run += v1;
            offs[(k + 2) * nBuck + b] = run; run += v2;
            offs[(k + 3) * nBuck + b] = run; run += v3;
        }
    }
    if (b == 0) bucketBase[nBuck] = nEdges;
}

// ---- sort stage 3: partition into coarse buckets, line-dense runs ----
__global__ void part_kernel(const int* __restrict__ src, const int* __restrict__ dst,
                            const int* __restrict__ et, const float* __restrict__ norm,
                            const int* __restrict__ offs, uint2* __restrict__ staged,
                            int nEdges, int nBuck, int chunk) {
    __shared__ int cur[512];
    for (int t = threadIdx.x; t < nBuck; t += 256)
        cur[t] = offs[blockIdx.x * nBuck + t];
    __syncthreads();
    int start = blockIdx.x * chunk;
    int end = min(nEdges, start + chunk);
    for (int i = start + threadIdx.x; i < end; i += 256) {
        int d = dst[i];
        int b = d >> BSH;
        int p = atomicAdd(&cur[b], 1);
        staged[p] = make_uint2(((unsigned)(d & 511) << 21) |
                               ((unsigned)src[i] << 3) | (unsigned)et[i],
                               __float_as_uint(norm[i]));
    }
}

// ---- sort stage 4: per-bucket exact sort in LDS; in-place meta rewrite + endOff ----
__global__ void sortB_kernel(uint2* __restrict__ meta, const int* __restrict__ bucketBase,
                             int* __restrict__ endOff, int nNodes) {
    const int b = blockIdx.x;
    const int tid = threadIdx.x;
    const int e0 = bucketBase[b];
    const int n = min(bucketBase[b + 1] - e0, BCAP);
    __shared__ uint2 st[BCAP];
    __shared__ int h[512];
    __shared__ int pb[256];
    h[2 * tid] = 0; h[2 * tid + 1] = 0;
    __syncthreads();
    for (int j = tid; j < n; j += 256) {
        uint2 v = meta[e0 + j];
        st[j] = v;
        atomicAdd(&h[v.x >> 21], 1);
    }
    __syncthreads();
    int h0 = h[2 * tid], h1v = h[2 * tid + 1];
    int ps = h0 + h1v;
    pb[tid] = ps;
    __syncthreads();
    for (int s = 1; s < 256; s <<= 1) {
        int t = (tid >= s) ? pb[tid - s] : 0;
        __syncthreads();
        pb[tid] += t;
        __syncthreads();
    }
    int ex = pb[tid] - ps;     // exclusive pair base
    int d0 = b << BSH;
    int dA = d0 + 2 * tid, dB = dA + 1;
    if (dA < nNodes) endOff[dA] = e0 + ex + h0;
    if (dB < nNodes) endOff[dB] = e0 + ex + ps;
    h[2 * tid] = ex;
    h[2 * tid + 1] = ex + h0;
    __syncthreads();
    for (int j = tid; j < n; j += 256) {
        uint2 v = st[j];
        int r = atomicAdd(&h[v.x >> 21], 1);
        meta[e0 + r] = make_uint2(v.x & 0x1FFFFFu, v.y);
    }
}

// ---- dense transform: Y[row, gg*128 + 8*ml + q] via 16B full-line stores (R8) ----
template <int G128, bool BF16IN>
__global__ __launch_bounds__(256) void transform_kernel(
    const void* __restrict__ xin, const short* __restrict__ Wf,
    ushort* __restrict__ yb, int nNodes) {
    constexpr int TOUT = G128 * 128;
    const int lane = threadIdx.x & 63;
    const int wid = (blockIdx.x * blockDim.x + threadIdx.x) >> 6;
    const int base = wid * 64;
    if (base >= nNodes) return;
    const int ml = lane & 15, kg = lane >> 4;

    short8v A[4][2];
#pragma unroll
    for (int s = 0; s < 4; ++s) {
        int row = min(base + s * 16 + ml, nNodes - 1);
        if (BF16IN) {
            const ushort* xp = (const ushort*)xin + (size_t)row * 64 + kg * 8;
            A[s][0] = *(const short8v*)xp;
            A[s][1] = *(const short8v*)(xp + 32);
        } else {
            const float* xp = (const float*)xin + (size_t)row * 64 + kg * 8;
            float4 f0 = *(const float4*)xp;
            float4 f1 = *(const float4*)(xp + 4);
            float4 f2 = *(const float4*)(xp + 32);
            float4 f3 = *(const float4*)(xp + 36);
            A[s][0] = cvt8(f0, f1);
            A[s][1] = cvt8(f2, f3);
        }
    }
#pragma unroll
    for (int gg = 0; gg < G128; ++gg) {
        const short* wp = Wf + (size_t)gg * 16 * 512 + lane * 8;
#pragma unroll
        for (int s = 0; s < 4; ++s) {
            f32x4 acc[8];
#pragma unroll
            for (int q = 0; q < 8; ++q) {
                short8v B0 = *(const short8v*)(wp + (q * 2 + 0) * 512);
                short8v B1 = *(const short8v*)(wp + (q * 2 + 1) * 512);
                acc[q] = __builtin_amdgcn_mfma_f32_16x16x32_bf16(A[s][0], B0,
                                                                 (f32x4){0.f, 0.f, 0.f, 0.f}, 0, 0, 0);
                acc[q] = __builtin_amdgcn_mfma_f32_16x16x32_bf16(A[s][1], B1, acc[q], 0, 0, 0);
            }
#pragma unroll
            for (int i = 0; i < 4; ++i) {
                int row = base + s * 16 + kg * 4 + i;
                if (row < nNodes) {
                    uint4 pk;
                    pk.x = (unsigned)(ushort)bfc(acc[0][i]) | ((unsigned)(ushort)bfc(acc[1][i]) << 16);
                    pk.y = (unsigned)(ushort)bfc(acc[2][i]) | ((unsigned)(ushort)bfc(acc[3][i]) << 16);
                    pk.z = (unsigned)(ushort)bfc(acc[4][i]) | ((unsigned)(ushort)bfc(acc[5][i]) << 16);
                    pk.w = (unsigned)(ushort)bfc(acc[6][i]) | ((unsigned)(ushort)bfc(acc[7][i]) << 16);
                    *reinterpret_cast<uint4*>(yb + (size_t)row * TOUT + gg * 128 + ml * 8) = pk;
                }
            }
        }
    }
}

// ---- edge aggregation: dst-range groups, 8-edge block pipeline (batched gathers).
// Per block: issue 8 gathers for blk+1 and 8 clamped meta loads for blk+2 (all
// independent), then consume blk (fma + boundary flush). Static register arrays.
template <int OUT, typename OutT, bool ACCUM, bool FILTER, int SHIFT>
__global__ __launch_bounds__(256, 4) void edge_kernel(
    const ushort* __restrict__ yb, const uint2* __restrict__ meta,
    const int* __restrict__ endOff, const float* __restrict__ bias,
    OutT* __restrict__ out, int nNodes, int D, int rtLo) {
    const int lane = threadIdx.x & 63;
    constexpr int GPW = 64 / OUT;
    const int wid = (blockIdx.x * blockDim.x + threadIdx.x) >> 6;
    const int sub = (GPW == 2) ? (lane >> 5) : 0;
    const int gbase = sub << 5;
    const int gid = wid * GPW + sub;
    const int o = lane & (OUT - 1);
    const int d0 = gid * D;
    if (d0 >= nNodes) return;
    const int d1 = min(d0 + D, nNodes);
    const float bv = bias[o];

    int bndv = 0x7fffffff;
    if (o < D) bndv = endOff[min(d0 + o, nNodes - 1)];
    const int eEnd = __shfl(bndv, gbase + (d1 - 1 - d0));
    int e = (d0 == 0) ? 0 : endOff[d0 - 1];
    int dcur = d0;
    int bnd = __shfl(bndv, gbase);
    float acc = 0.f;

    auto gv = [&](unsigned key) -> float {
        if (FILTER) {
            int rr = (int)(key & 7u) - rtLo;
            if ((unsigned)rr >= 4u) return 0.f;
            unsigned off = (((key >> 3) * (unsigned)(4 * OUT)) +
                            (unsigned)rr * OUT + (unsigned)o) << 1;
            return bf2f(*(const ushort*)((const char*)yb + off));
        } else {
            unsigned off = (key << SHIFT) + ((unsigned)o << 1);
            return bf2f(*(const ushort*)((const char*)yb + off));
        }
    };
    auto flush = [&](int d, float a) {
        size_t idx = (size_t)d * OUT + o;
        if constexpr (ACCUM) {
            out[idx] = (OutT)(ushort)bfc(bf2f((ushort)out[idx]) + a);
        } else if constexpr (sizeof(OutT) == 2) {
            out[idx] = (OutT)(ushort)bfc(bv + a);
        } else {
            out[idx] = (OutT)(bv + a);
        }
    };

    if (e < eEnd) {
        const int eL = eEnd - 1;
        uint2 Ma[8], Mb[8];
        float Va[8];
#pragma unroll
        for (int k = 0; k < 8; ++k) Ma[k] = meta[min(e + k, eL)];
#pragma unroll
        for (int k = 0; k < 8; ++k) Mb[k] = meta[min(e + 8 + k, eL)];
#pragma unroll
        for (int k = 0; k < 8; ++k) Va[k] = gv(Ma[k].x);

        const int nFull = (eEnd - e) >> 3;
#pragma unroll 2
        for (int blk = 0; blk < nFull; ++blk) {
            float Vb[8];
            uint2 Mc[8];
#pragma unroll
            for (int k = 0; k < 8; ++k) Vb[k] = gv(Mb[k].x);      // gathers blk+1
#pragma unroll
            for (int k = 0; k < 8; ++k) Mc[k] = meta[min(e + 16 + k, eL)];  // meta blk+2
#pragma unroll
            for (int k = 0; k < 8; ++k) {                          // consume blk
                while (e >= bnd) {
                    flush(dcur, acc);
                    acc = 0.f;
                    ++dcur;
                    bnd = __shfl(bndv, gbase + (dcur - d0));
                }
                acc = fmaf(__uint_as_float(Ma[k].y), Va[k], acc);
                ++e;
            }
#pragma unroll
            for (int k = 0; k < 8; ++k) { Ma[k] = Mb[k]; Mb[k] = Mc[k]; Va[k] = Vb[k]; }
        }
        // tail (< 8 edges): data already resident in Ma/Va
        const int rem = eEnd - e;
#pragma unroll
        for (int k = 0; k < 8; ++k) {
            if (k < rem) {
                while (e >= bnd) {
                    flush(dcur, acc);
                    acc = 0.f;
                    ++dcur;
                    bnd = __shfl(bndv, gbase + (dcur - d0));
                }
                acc = fmaf(__uint_as_float(Ma[k].y), Va[k], acc);
                ++e;
            }
        }
    }
    for (; dcur < d1; ++dcur) {
        flush(dcur, acc);
        acc = 0.f;
    }
}

extern "C" void kernel_launch(void* const* d_in, const int* in_sizes, int n_in,
                              void* d_out, int out_size, void* d_ws, size_t ws_size,
                              hipStream_t stream) {
    const float* emb    = (const float*)d_in[0];
    const float* basis1 = (const float*)d_in[1];
    const float* comp1  = (const float*)d_in[2];
    const float* bias1  = (const float*)d_in[3];
    const float* basis2 = (const float*)d_in[4];
    const float* comp2  = (const float*)d_in[5];
    const float* bias2  = (const float*)d_in[6];
    const int*   src    = (const int*)d_in[7];
    const int*   dst    = (const int*)d_in[8];
    const int*   etype  = (const int*)d_in[9];
    const float* norm   = (const float*)d_in[10];
    float* out = (float*)d_out;

    const int nNodes = in_sizes[0] / 64;   // 200000
    const int nEdges = in_sizes[7];        // 1000000

    const int nBuck = (nNodes + 511) >> BSH;            // 391
    const int chunk = (nEdges + PBLK - 1) / PBLK;       // 7813

    char* ws = (char*)d_ws;
    short* Wf1        = (short*)(ws);                               // 64 KB
    short* Wf2        = (short*)(ws + 65536);                       // 32 KB
    int*   histM      = (int*)(ws + 98304);                         // 200,192 B
    int*   offs       = (int*)(ws + 298496);                        // 200,192 B
    int*   bucketBase = (int*)(ws + 498688);                        // 1,568 B
    int*   endOff     = (int*)(ws + 500480);                        // 800,000 B
    size_t offMeta = 1300480;
    uint2* meta       = (uint2*)(ws + offMeta);                     // 8 MB
    size_t offY = offMeta + (size_t)nEdges * 8;

    const size_t yFused = (size_t)nNodes * 512 * 2;  // 204.8 MB
    const size_t yHalf  = (size_t)nNodes * 256 * 2;  // 102.4 MB
    const size_t h1Sz   = (size_t)nNodes * 64 * 2;   // 25.6 MB
    const bool fused = ws_size >= offY + yFused + h1Sz;
    const size_t ySz = fused ? yFused : yHalf;
    ushort* yB  = (ushort*)(ws + offY);
    ushort* h1b = (ushort*)(ws + offY + ySz);

    // ---- sort (no global atomics, line-dense writes) ----
    wprep_kernel<<<192, 256, 0, stream>>>(basis1, comp1, basis2, comp2, Wf1, Wf2);
    histA_kernel<<<PBLK, 256, 0, stream>>>(dst, histM, nEdges, nBuck, chunk);
    scanA_kernel<<<1, 512, 0, stream>>>(histM, offs, bucketBase, nBuck, PBLK, nEdges);
    part_kernel<<<PBLK, 256, 0, stream>>>(src, dst, etype, norm, offs, meta,
                                          nEdges, nBuck, chunk);
    sortB_kernel<<<nBuck, 256, 0, stream>>>(meta, bucketBase, endOff, nNodes);

    const int tBlocks = (((nNodes + 63) / 64) + 3) / 4;
    const int D = 8;
    const int nGroups = (nNodes + D - 1) / D;
    const int b64 = (nGroups + 3) / 4;
    const int b32 = (nGroups + 7) / 8;

    if (fused) {
        transform_kernel<4, false><<<tBlocks, 256, 0, stream>>>(emb, Wf1, yB, nNodes);
        edge_kernel<64, ushort, false, false, 7><<<b64, 256, 0, stream>>>(
            yB, meta, endOff, bias1, h1b, nNodes, D, 0);
    } else {
        transform_kernel<2, false><<<tBlocks, 256, 0, stream>>>(emb, Wf1, yB, nNodes);
        edge_kernel<64, ushort, false, true, 0><<<b64, 256, 0, stream>>>(
            yB, meta, endOff, bias1, h1b, nNodes, D, 0);
        transform_kernel<2, false><<<tBlocks, 256, 0, stream>>>(emb, Wf1 + 16384, yB, nNodes);
        edge_kernel<64, ushort, true, true, 0><<<b64, 256, 0, stream>>>(
            yB, meta, endOff, bias1, h1b, nNodes, D, 4);
    }
    // ---- layer 2 ----
    transform_kernel<2, true><<<tBlocks, 256, 0, stream>>>(h1b, Wf2, yB, nNodes);
    edge_kernel<32, float, false, false, 6><<<b32, 256, 0, stream>>>(
        yB, meta, endOff, bias2, out, nNodes, D, 0);
}

// Round 11
// 262.623 us; speedup vs baseline: 3.8017x; 1.0167x over previous
//
#include <hip/hip_runtime.h>
#include <hip/hip_bf16.h>

#define NRELS 8
#define NB 8
#define PBLK 128          // partition blocks
#define BSH 9             // dsts per bucket = 512
#define BCAP 3584         // max edges per bucket staged in LDS

typedef __attribute__((ext_vector_type(8))) short short8v;
typedef __attribute__((ext_vector_type(4))) float f32x4;

__device__ __forceinline__ short bfc(float f) {
    __hip_bfloat16 h = __float2bfloat16(f);
    return *reinterpret_cast<short*>(&h);
}
__device__ __forceinline__ float bf2f(ushort u) {
    return __uint_as_float((unsigned)u << 16);
}
__device__ __forceinline__ short8v cvt8(float4 a, float4 b) {
    short8v r;
    r[0] = bfc(a.x); r[1] = bfc(a.y); r[2] = bfc(a.z); r[3] = bfc(a.w);
    r[4] = bfc(b.x); r[5] = bfc(b.y); r[6] = bfc(b.z); r[7] = bfc(b.w);
    return r;
}

// ---- W in MFMA B-frag order, 8-consecutive-col-per-lane packing (verified R8).
__global__ void wprep_kernel(const float* __restrict__ basis1, const float* __restrict__ comp1,
                             const float* __restrict__ basis2, const float* __restrict__ comp2,
                             short* __restrict__ Wf1, short* __restrict__ Wf2) {
    int idx = blockIdx.x * blockDim.x + threadIdx.x;
    const int n1 = 64 * 512;
    const int n2 = 32 * 512;
    if (idx < n1) {
        int f = idx >> 9, lane = (idx >> 3) & 63, j = idx & 7;
        int ks = f & 1, q = (f >> 1) & 7, gg = f >> 4;
        int c = gg * 128 + 8 * (lane & 15) + q;
        int k = ks * 32 + (lane >> 4) * 8 + j;
        int r = c >> 6, crel = c & 63;
        float s = 0.f;
#pragma unroll
        for (int b = 0; b < NB; ++b)
            s = fmaf(comp1[r * NB + b], basis1[b * 4096 + k * 64 + crel], s);
        Wf1[idx] = bfc(s);
    } else if (idx < n1 + n2) {
        int i2 = idx - n1;
        int f = i2 >> 9, lane = (i2 >> 3) & 63, j = i2 & 7;
        int ks = f & 1, q = (f >> 1) & 7, gg = f >> 4;
        int c = gg * 128 + 8 * (lane & 15) + q;
        int k = ks * 32 + (lane >> 4) * 8 + j;
        int r = c >> 5, crel = c & 31;
        float s = 0.f;
#pragma unroll
        for (int b = 0; b < NB; ++b)
            s = fmaf(comp2[r * NB + b], basis2[b * 2048 + k * 32 + crel], s);
        Wf2[i2] = bfc(s);
    }
}

// ---- sort stage 1: per-block coarse histogram; histM layout [bucket][block] ----
__global__ void histA_kernel(const int* __restrict__ dst, int* __restrict__ histM,
                             int nEdges, int nBuck, int chunk) {
    __shared__ int h[512];
    for (int t = threadIdx.x; t < nBuck; t += 256) h[t] = 0;
    __syncthreads();
    int start = blockIdx.x * chunk;
    int end = min(nEdges, start + chunk);
    for (int i = start + threadIdx.x; i < end; i += 256)
        atomicAdd(&h[dst[i] >> BSH], 1);
    __syncthreads();
    for (int t = threadIdx.x; t < nBuck; t += 256)
        histM[t * PBLK + blockIdx.x] = h[t];
}

// ---- sort stage 2: per-bucket totals scan -> bucketBase; per-(bucket,block) offs.
// histM/offs transposed [bucket][block]: contiguous int4 loads+stores per thread.
__global__ void scanA_kernel(const int* __restrict__ histM, int* __restrict__ offs,
                             int* __restrict__ bucketBase, int nBuck, int nBlk, int nEdges) {
    __shared__ int tot[512];
    const int b = threadIdx.x;
    int s = 0;
    if (b < nBuck) {
        const int4* hp = (const int4*)(histM + b * nBlk);
        for (int k = 0; k < nBlk / 4; ++k) {
            int4 v = hp[k];
            s += v.x + v.y + v.z + v.w;
        }
    }
    tot[b] = s;
    __syncthreads();
    int own = s;
    for (int st = 1; st < 512; st <<= 1) {
        int t = (b >= st) ? tot[b - st] : 0;
        __syncthreads();
        tot[b] += t;
        __syncthreads();
    }
    int base = tot[b] - own;   // exclusive
    if (b < nBuck) {
        bucketBase[b] = base;
        int run = base;
        const int4* hp = (const int4*)(histM + b * nBlk);
        int4* op = (int4*)(offs + b * nBlk);
        for (int k = 0; k < nBlk / 4; ++k) {
            int4 h4 = hp[k];
            int4 o4;
            o4.x = run; run += h4.x;
            o4.y = run; run += h4.y;
            o4.z = run; run += h4.z;
            o4.w = run; run += h4.w;
            op[k] = o4;
        }
    }
    if (b == 0) bucketBase[nBuck] = nEdges;
}

// ---- sort stage 3: partition into coarse buckets, line-dense runs ----
__global__ void part_kernel(const int* __restrict__ src, const int* __restrict__ dst,
                            const int* __restrict__ et, const float* __restrict__ norm,
                            const int* __restrict__ offs, uint2* __restrict__ staged,
                            int nEdges, int nBuck, int chunk) {
    __shared__ int cur[512];
    for (int t = threadIdx.x; t < nBuck; t += 256)
        cur[t] = offs[t * PBLK + blockIdx.x];
    __syncthreads();
    int start = blockIdx.x * chunk;
    int end = min(nEdges, start + chunk);
    for (int i = start + threadIdx.x; i < end; i += 256) {
        int d = dst[i];
        int b = d >> BSH;
        int p = atomicAdd(&cur[b], 1);
        staged[p] = make_uint2(((unsigned)(d & 511) << 21) |
                               ((unsigned)src[i] << 3) | (unsigned)et[i],
                               __float_as_uint(norm[i]));
    }
}

// ---- sort stage 4: per-bucket exact sort in LDS; in-place meta rewrite + endOff ----
__global__ void sortB_kernel(uint2* __restrict__ meta, const int* __restrict__ bucketBase,
                             int* __restrict__ endOff, int nNodes) {
    const int b = blockIdx.x;
    const int tid = threadIdx.x;
    const int e0 = bucketBase[b];
    const int n = min(bucketBase[b + 1] - e0, BCAP);
    __shared__ uint2 st[BCAP];
    __shared__ int h[512];
    __shared__ int pb[256];
    h[2 * tid] = 0; h[2 * tid + 1] = 0;
    __syncthreads();
    for (int j = tid; j < n; j += 256) {
        uint2 v = meta[e0 + j];
        st[j] = v;
        atomicAdd(&h[v.x >> 21], 1);
    }
    __syncthreads();
    int h0 = h[2 * tid], h1v = h[2 * tid + 1];
    int ps = h0 + h1v;
    pb[tid] = ps;
    __syncthreads();
    for (int s = 1; s < 256; s <<= 1) {
        int t = (tid >= s) ? pb[tid - s] : 0;
        __syncthreads();
        pb[tid] += t;
        __syncthreads();
    }
    int ex = pb[tid] - ps;     // exclusive pair base
    int d0 = b << BSH;
    int dA = d0 + 2 * tid, dB = dA + 1;
    if (dA < nNodes) endOff[dA] = e0 + ex + h0;
    if (dB < nNodes) endOff[dB] = e0 + ex + ps;
    h[2 * tid] = ex;
    h[2 * tid + 1] = ex + h0;
    __syncthreads();
    for (int j = tid; j < n; j += 256) {
        uint2 v = st[j];
        int r = atomicAdd(&h[v.x >> 21], 1);
        meta[e0 + r] = make_uint2(v.x & 0x1FFFFFu, v.y);
    }
}

// ---- dense transform: 32 nodes/wave (2 subtiles), B-frags loaded once per gg ----
template <int G128, bool BF16IN>
__global__ __launch_bounds__(256) void transform_kernel(
    const void* __restrict__ xin, const short* __restrict__ Wf,
    ushort* __restrict__ yb, int nNodes) {
    constexpr int TOUT = G128 * 128;
    const int lane = threadIdx.x & 63;
    const int wid = (blockIdx.x * blockDim.x + threadIdx.x) >> 6;
    const int base = wid * 32;
    if (base >= nNodes) return;
    const int ml = lane & 15, kg = lane >> 4;

    short8v A[2][2];
#pragma unroll
    for (int s = 0; s < 2; ++s) {
        int row = min(base + s * 16 + ml, nNodes - 1);
        if (BF16IN) {
            const ushort* xp = (const ushort*)xin + (size_t)row * 64 + kg * 8;
            A[s][0] = *(const short8v*)xp;
            A[s][1] = *(const short8v*)(xp + 32);
        } else {
            const float* xp = (const float*)xin + (size_t)row * 64 + kg * 8;
            float4 f0 = *(const float4*)xp;
            float4 f1 = *(const float4*)(xp + 4);
            float4 f2 = *(const float4*)(xp + 32);
            float4 f3 = *(const float4*)(xp + 36);
            A[s][0] = cvt8(f0, f1);
            A[s][1] = cvt8(f2, f3);
        }
    }
#pragma unroll
    for (int gg = 0; gg < G128; ++gg) {
        const short* wp = Wf + (size_t)gg * 16 * 512 + lane * 8;
        f32x4 acc[2][8];
#pragma unroll
        for (int q = 0; q < 8; ++q) {
            short8v B0 = *(const short8v*)(wp + (q * 2 + 0) * 512);
            short8v B1 = *(const short8v*)(wp + (q * 2 + 1) * 512);
#pragma unroll
            for (int s = 0; s < 2; ++s) {
                acc[s][q] = __builtin_amdgcn_mfma_f32_16x16x32_bf16(A[s][0], B0,
                                                                    (f32x4){0.f, 0.f, 0.f, 0.f}, 0, 0, 0);
                acc[s][q] = __builtin_amdgcn_mfma_f32_16x16x32_bf16(A[s][1], B1, acc[s][q], 0, 0, 0);
            }
        }
#pragma unroll
        for (int s = 0; s < 2; ++s) {
#pragma unroll
            for (int i = 0; i < 4; ++i) {
                int row = base + s * 16 + kg * 4 + i;
                if (row < nNodes) {
                    uint4 pk;
                    pk.x = (unsigned)(ushort)bfc(acc[s][0][i]) | ((unsigned)(ushort)bfc(acc[s][1][i]) << 16);
                    pk.y = (unsigned)(ushort)bfc(acc[s][2][i]) | ((unsigned)(ushort)bfc(acc[s][3][i]) << 16);
                    pk.z = (unsigned)(ushort)bfc(acc[s][4][i]) | ((unsigned)(ushort)bfc(acc[s][5][i]) << 16);
                    pk.w = (unsigned)(ushort)bfc(acc[s][6][i]) | ((unsigned)(ushort)bfc(acc[s][7][i]) << 16);
                    *reinterpret_cast<uint4*>(yb + (size_t)row * TOUT + gg * 128 + ml * 8) = pk;
                }
            }
        }
    }
}

// ---- edge aggregation: mod-3 register-set pipeline, no rotation movs.
// Main loop (e+40<=eEnd): 3 unclamped phases/iter. Tail: <=5 clamped phases.
template <int OUT, typename OutT, bool ACCUM, bool FILTER, int SHIFT>
__global__ __launch_bounds__(256, 4) void edge_kernel(
    const ushort* __restrict__ yb, const uint2* __restrict__ meta,
    const int* __restrict__ endOff, const float* __restrict__ bias,
    OutT* __restrict__ out, int nNodes, int D, int rtLo) {
    const int lane = threadIdx.x & 63;
    constexpr int GPW = 64 / OUT;
    const int wid = (blockIdx.x * blockDim.x + threadIdx.x) >> 6;
    const int sub = (GPW == 2) ? (lane >> 5) : 0;
    const int gbase = sub << 5;
    const int gid = wid * GPW + sub;
    const int o = lane & (OUT - 1);
    const int d0 = gid * D;
    if (d0 >= nNodes) return;
    const int d1 = min(d0 + D, nNodes);
    const float bv = bias[o];

    int bndv = 0x7fffffff;
    if (o < D) bndv = endOff[min(d0 + o, nNodes - 1)];
    const int eEnd = __shfl(bndv, gbase + (d1 - 1 - d0));
    int e = (d0 == 0) ? 0 : endOff[d0 - 1];
    int dcur = d0;
    int bnd = __shfl(bndv, gbase);
    float acc = 0.f;

    const char* ybo = (const char*)yb + ((unsigned)o << 1);
    auto gv = [&](unsigned key) -> float {
        if (FILTER) {
            int rr = (int)(key & 7u) - rtLo;
            if ((unsigned)rr >= 4u) return 0.f;
            unsigned off = (((key >> 3) * (unsigned)(4 * OUT)) +
                            (unsigned)rr * OUT) << 1;
            return bf2f(*(const ushort*)(ybo + off));
        } else {
            return bf2f(*(const ushort*)(ybo + ((size_t)(key << SHIFT))));
        }
    };
    auto flush = [&](int d, float a) {
        size_t idx = (size_t)d * OUT + o;
        if constexpr (ACCUM) {
            out[idx] = (OutT)(ushort)bfc(bf2f((ushort)out[idx]) + a);
        } else if constexpr (sizeof(OutT) == 2) {
            out[idx] = (OutT)(ushort)bfc(bv + a);
        } else {
            out[idx] = (OutT)(bv + a);
        }
    };

    if (e < eEnd) {
        const int eL = eEnd - 1;
        uint2 M0[8], M1[8], M2[8];
        float V0[8], V1[8], V2[8];

#pragma unroll
        for (int k = 0; k < 8; ++k) M0[k] = meta[min(e + k, eL)];
#pragma unroll
        for (int k = 0; k < 8; ++k) M1[k] = meta[min(e + 8 + k, eL)];
#pragma unroll
        for (int k = 0; k < 8; ++k) V0[k] = gv(M0[k].x);

        // main phase: gather NXT values, consume CUR, refill NN with unclamped meta
#define PHASE(CUR, NXT, NN)                                                   \
        {                                                                     \
            _Pragma("unroll")                                                 \
            for (int k = 0; k < 8; ++k) V##NXT[k] = gv(M##NXT[k].x);          \
            _Pragma("unroll")                                                 \
            for (int k = 0; k < 8; ++k) {                                     \
                while (e >= bnd) {                                            \
                    flush(dcur, acc); acc = 0.f; ++dcur;                      \
                    bnd = __shfl(bndv, gbase + (dcur - d0));                  \
                }                                                             \
                acc = fmaf(__uint_as_float(M##CUR[k].y), V##CUR[k], acc);     \
                ++e;                                                          \
            }                                                                 \
            _Pragma("unroll")                                                 \
            for (int k = 0; k < 8; ++k) M##NN[k] = meta[e + 8 + k];           \
        }

        while (e + 40 <= eEnd) {
            PHASE(0, 1, 2)
            PHASE(1, 2, 0)
            PHASE(2, 0, 1)
        }

        // tail phase: clamped meta refill, partial consume
#define TPHASE(CUR, NXT, NN)                                                  \
        if (e < eEnd) {                                                       \
            _Pragma("unroll")                                                 \
            for (int k = 0; k < 8; ++k) V##NXT[k] = gv(M##NXT[k].x);          \
            int c = eEnd - e; if (c > 8) c = 8;                               \
            _Pragma("unroll")                                                 \
            for (int k = 0; k < 8; ++k) {                                     \
                if (k < c) {                                                  \
                    while (e >= bnd) {                                        \
                        flush(dcur, acc); acc = 0.f; ++dcur;                  \
                        bnd = __shfl(bndv, gbase + (dcur - d0));              \
                    }                                                         \
                    acc = fmaf(__uint_as_float(M##CUR[k].y), V##CUR[k], acc); \
                    ++e;                                                      \
                }                                                             \
            }                                                                 \
            _Pragma("unroll")                                                 \
            for (int k = 0; k < 8; ++k) M##NN[k] = meta[min(e + 8 + k, eL)];  \
        }

        TPHASE(0, 1, 2)
        TPHASE(1, 2, 0)
        TPHASE(2, 0, 1)
        TPHASE(0, 1, 2)
        TPHASE(1, 2, 0)
#undef PHASE
#undef TPHASE
    }
    for (; dcur < d1; ++dcur) {
        flush(dcur, acc);
        acc = 0.f;
    }
}

extern "C" void kernel_launch(void* const* d_in, const int* in_sizes, int n_in,
                              void* d_out, int out_size, void* d_ws, size_t ws_size,
                              hipStream_t stream) {
    const float* emb    = (const float*)d_in[0];
    const float* basis1 = (const float*)d_in[1];
    const float* comp1  = (const float*)d_in[2];
    const float* bias1  = (const float*)d_in[3];
    const float* basis2 = (const float*)d_in[4];
    const float* comp2  = (const float*)d_in[5];
    const float* bias2  = (const float*)d_in[6];
    const int*   src    = (const int*)d_in[7];
    const int*   dst    = (const int*)d_in[8];
    const int*   etype  = (const int*)d_in[9];
    const float* norm   = (const float*)d_in[10];
    float* out = (float*)d_out;

    const int nNodes = in_sizes[0] / 64;   // 200000
    const int nEdges = in_sizes[7];        // 1000000

    const int nBuck = (nNodes + 511) >> BSH;            // 391
    const int chunk = (nEdges + PBLK - 1) / PBLK;       // 7813

    char* ws = (char*)d_ws;
    short* Wf1        = (short*)(ws);                               // 64 KB
    short* Wf2        = (short*)(ws + 65536);                       // 32 KB
    int*   histM      = (int*)(ws + 98304);                         // 200,192 B
    int*   offs       = (int*)(ws + 298496);                        // 200,192 B
    int*   bucketBase = (int*)(ws + 498688);                        // 1,568 B
    int*   endOff     = (int*)(ws + 500480);                        // 800,000 B
    size_t offMeta = 1300480;
    uint2* meta       = (uint2*)(ws + offMeta);                     // 8 MB
    size_t offY = offMeta + (size_t)nEdges * 8;

    const size_t yFused = (size_t)nNodes * 512 * 2;  // 204.8 MB
    const size_t yHalf  = (size_t)nNodes * 256 * 2;  // 102.4 MB
    const size_t h1Sz   = (size_t)nNodes * 64 * 2;   // 25.6 MB
    const bool fused = ws_size >= offY + yFused + h1Sz;
    const size_t ySz = fused ? yFused : yHalf;
    ushort* yB  = (ushort*)(ws + offY);
    ushort* h1b = (ushort*)(ws + offY + ySz);

    // ---- sort (no global atomics, line-dense writes) ----
    wprep_kernel<<<192, 256, 0, stream>>>(basis1, comp1, basis2, comp2, Wf1, Wf2);
    histA_kernel<<<PBLK, 256, 0, stream>>>(dst, histM, nEdges, nBuck, chunk);
    scanA_kernel<<<1, 512, 0, stream>>>(histM, offs, bucketBase, nBuck, PBLK, nEdges);
    part_kernel<<<PBLK, 256, 0, stream>>>(src, dst, etype, norm, offs, meta,
                                          nEdges, nBuck, chunk);
    sortB_kernel<<<nBuck, 256, 0, stream>>>(meta, bucketBase, endOff, nNodes);

    const int tBlocks = (((nNodes + 31) / 32) + 3) / 4;   // 32 nodes per wave
    const int D = 8;
    const int nGroups = (nNodes + D - 1) / D;
    const int b64 = (nGroups + 3) / 4;
    const int b32 = (nGroups + 7) / 8;

    if (fused) {
        transform_kernel<4, false><<<tBlocks, 256, 0, stream>>>(emb, Wf1, yB, nNodes);
        edge_kernel<64, ushort, false, false, 7><<<b64, 256, 0, stream>>>(
            yB, meta, endOff, bias1, h1b, nNodes, D, 0);
    } else {
        transform_kernel<2, false><<<tBlocks, 256, 0, stream>>>(emb, Wf1, yB, nNodes);
        edge_kernel<64, ushort, false, true, 0><<<b64, 256, 0, stream>>>(
            yB, meta, endOff, bias1, h1b, nNodes, D, 0);
        transform_kernel<2, false><<<tBlocks, 256, 0, stream>>>(emb, Wf1 + 16384, yB, nNodes);
        edge_kernel<64, ushort, true, true, 0><<<b64, 256, 0, stream>>>(
            yB, meta, endOff, bias1, h1b, nNodes, D, 4);
    }
    // ---- layer 2 ----
    transform_kernel<2, true><<<tBlocks, 256, 0, stream>>>(h1b, Wf2, yB, nNodes);
    edge_kernel<32, float, false, false, 6><<<b32, 256, 0, stream>>>(
        yB, meta, endOff, bias2, out, nNodes, D, 0);
}

// Round 12
// 244.063 us; speedup vs baseline: 4.0908x; 1.0760x over previous
//
#include <hip/hip_runtime.h>
#include <hip/hip_bf16.h>

#define NRELS 8
#define NB 8
#define PBLK 256          // partition blocks
#define BSH 9             // dsts per bucket = 512
#define BCAP 3584         // max edges per bucket staged in LDS

typedef __attribute__((ext_vector_type(8))) short short8v;
typedef __attribute__((ext_vector_type(4))) float f32x4;

__device__ __forceinline__ short bfc(float f) {
    __hip_bfloat16 h = __float2bfloat16(f);
    return *reinterpret_cast<short*>(&h);
}
__device__ __forceinline__ float bf2f(ushort u) {
    return __uint_as_float((unsigned)u << 16);
}
__device__ __forceinline__ short8v cvt8(float4 a, float4 b) {
    short8v r;
    r[0] = bfc(a.x); r[1] = bfc(a.y); r[2] = bfc(a.z); r[3] = bfc(a.w);
    r[4] = bfc(b.x); r[5] = bfc(b.y); r[6] = bfc(b.z); r[7] = bfc(b.w);
    return r;
}

// ---- W in MFMA B-frag order, 8-consecutive-col-per-lane packing (verified R8).
__global__ void wprep_kernel(const float* __restrict__ basis1, const float* __restrict__ comp1,
                             const float* __restrict__ basis2, const float* __restrict__ comp2,
                             short* __restrict__ Wf1, short* __restrict__ Wf2) {
    int idx = blockIdx.x * blockDim.x + threadIdx.x;
    const int n1 = 64 * 512;
    const int n2 = 32 * 512;
    if (idx < n1) {
        int f = idx >> 9, lane = (idx >> 3) & 63, j = idx & 7;
        int ks = f & 1, q = (f >> 1) & 7, gg = f >> 4;
        int c = gg * 128 + 8 * (lane & 15) + q;
        int k = ks * 32 + (lane >> 4) * 8 + j;
        int r = c >> 6, crel = c & 63;
        float s = 0.f;
#pragma unroll
        for (int b = 0; b < NB; ++b)
            s = fmaf(comp1[r * NB + b], basis1[b * 4096 + k * 64 + crel], s);
        Wf1[idx] = bfc(s);
    } else if (idx < n1 + n2) {
        int i2 = idx - n1;
        int f = i2 >> 9, lane = (i2 >> 3) & 63, j = i2 & 7;
        int ks = f & 1, q = (f >> 1) & 7, gg = f >> 4;
        int c = gg * 128 + 8 * (lane & 15) + q;
        int k = ks * 32 + (lane >> 4) * 8 + j;
        int r = c >> 5, crel = c & 31;
        float s = 0.f;
#pragma unroll
        for (int b = 0; b < NB; ++b)
            s = fmaf(comp2[r * NB + b], basis2[b * 2048 + k * 32 + crel], s);
        Wf2[i2] = bfc(s);
    }
}

// ---- sort stage 1: per-block coarse histogram; histM layout [bucket][block] ----
__global__ void histA_kernel(const int* __restrict__ dst, int* __restrict__ histM,
                             int nEdges, int nBuck, int chunk) {
    __shared__ int h[512];
    for (int t = threadIdx.x; t < nBuck; t += 256) h[t] = 0;
    __syncthreads();
    int start = blockIdx.x * chunk;
    int end = min(nEdges, start + chunk);
    for (int i = start + threadIdx.x; i < end; i += 256)
        atomicAdd(&h[dst[i] >> BSH], 1);
    __syncthreads();
    for (int t = threadIdx.x; t < nBuck; t += 256)
        histM[t * PBLK + blockIdx.x] = h[t];
}

// ---- sort stage 2: per-bucket totals scan -> bucketBase; per-(bucket,block) offs ----
__global__ void scanA_kernel(const int* __restrict__ histM, int* __restrict__ offs,
                             int* __restrict__ bucketBase, int nBuck, int nBlk, int nEdges) {
    __shared__ int tot[512];
    const int b = threadIdx.x;
    int s = 0;
    if (b < nBuck) {
        const int4* hp = (const int4*)(histM + b * nBlk);
        for (int k = 0; k < nBlk / 4; ++k) {
            int4 v = hp[k];
            s += v.x + v.y + v.z + v.w;
        }
    }
    tot[b] = s;
    __syncthreads();
    int own = s;
    for (int st = 1; st < 512; st <<= 1) {
        int t = (b >= st) ? tot[b - st] : 0;
        __syncthreads();
        tot[b] += t;
        __syncthreads();
    }
    int base = tot[b] - own;   // exclusive
    if (b < nBuck) {
        bucketBase[b] = base;
        int run = base;
        const int4* hp = (const int4*)(histM + b * nBlk);
        int4* op = (int4*)(offs + b * nBlk);
        for (int k = 0; k < nBlk / 4; ++k) {
            int4 h4 = hp[k];
            int4 o4;
            o4.x = run; run += h4.x;
            o4.y = run; run += h4.y;
            o4.z = run; run += h4.z;
            o4.w = run; run += h4.w;
            op[k] = o4;
        }
    }
    if (b == 0) bucketBase[nBuck] = nEdges;
}

// ---- sort stage 3: partition into coarse buckets, line-dense runs ----
__global__ void part_kernel(const int* __restrict__ src, const int* __restrict__ dst,
                            const int* __restrict__ et, const float* __restrict__ norm,
                            const int* __restrict__ offs, uint2* __restrict__ staged,
                            int nEdges, int nBuck, int chunk) {
    __shared__ int cur[512];
    for (int t = threadIdx.x; t < nBuck; t += 256)
        cur[t] = offs[t * PBLK + blockIdx.x];
    __syncthreads();
    int start = blockIdx.x * chunk;
    int end = min(nEdges, start + chunk);
    for (int i = start + threadIdx.x; i < end; i += 256) {
        int d = dst[i];
        int b = d >> BSH;
        int p = atomicAdd(&cur[b], 1);
        staged[p] = make_uint2(((unsigned)(d & 511) << 21) |
                               ((unsigned)src[i] << 3) | (unsigned)et[i],
                               __float_as_uint(norm[i]));
    }
}

// ---- sort stage 4: per-bucket exact sort in LDS; in-place meta rewrite + endOff ----
__global__ void sortB_kernel(uint2* __restrict__ meta, const int* __restrict__ bucketBase,
                             int* __restrict__ endOff, int nNodes) {
    const int b = blockIdx.x;
    const int tid = threadIdx.x;
    const int e0 = bucketBase[b];
    const int n = min(bucketBase[b + 1] - e0, BCAP);
    __shared__ uint2 st[BCAP];
    __shared__ int h[512];
    __shared__ int pb[256];
    h[2 * tid] = 0; h[2 * tid + 1] = 0;
    __syncthreads();
    for (int j = tid; j < n; j += 256) {
        uint2 v = meta[e0 + j];
        st[j] = v;
        atomicAdd(&h[v.x >> 21], 1);
    }
    __syncthreads();
    int h0 = h[2 * tid], h1v = h[2 * tid + 1];
    int ps = h0 + h1v;
    pb[tid] = ps;
    __syncthreads();
    for (int s = 1; s < 256; s <<= 1) {
        int t = (tid >= s) ? pb[tid - s] : 0;
        __syncthreads();
        pb[tid] += t;
        __syncthreads();
    }
    int ex = pb[tid] - ps;     // exclusive pair base
    int d0 = b << BSH;
    int dA = d0 + 2 * tid, dB = dA + 1;
    if (dA < nNodes) endOff[dA] = e0 + ex + h0;
    if (dB < nNodes) endOff[dB] = e0 + ex + ps;
    h[2 * tid] = ex;
    h[2 * tid + 1] = ex + h0;
    __syncthreads();
    for (int j = tid; j < n; j += 256) {
        uint2 v = st[j];
        int r = atomicAdd(&h[v.x >> 21], 1);
        meta[e0 + r] = make_uint2(v.x & 0x1FFFFFu, v.y);
    }
}

// ---- dense transform: 32 nodes/wave (2 subtiles), B-frags loaded once per gg ----
template <int G128, bool BF16IN>
__global__ __launch_bounds__(256) void transform_kernel(
    const void* __restrict__ xin, const short* __restrict__ Wf,
    ushort* __restrict__ yb, int nNodes) {
    constexpr int TOUT = G128 * 128;
    const int lane = threadIdx.x & 63;
    const int wid = (blockIdx.x * blockDim.x + threadIdx.x) >> 6;
    const int base = wid * 32;
    if (base >= nNodes) return;
    const int ml = lane & 15, kg = lane >> 4;

    short8v A[2][2];
#pragma unroll
    for (int s = 0; s < 2; ++s) {
        int row = min(base + s * 16 + ml, nNodes - 1);
        if (BF16IN) {
            const ushort* xp = (const ushort*)xin + (size_t)row * 64 + kg * 8;
            A[s][0] = *(const short8v*)xp;
            A[s][1] = *(const short8v*)(xp + 32);
        } else {
            const float* xp = (const float*)xin + (size_t)row * 64 + kg * 8;
            float4 f0 = *(const float4*)xp;
            float4 f1 = *(const float4*)(xp + 4);
            float4 f2 = *(const float4*)(xp + 32);
            float4 f3 = *(const float4*)(xp + 36);
            A[s][0] = cvt8(f0, f1);
            A[s][1] = cvt8(f2, f3);
        }
    }
#pragma unroll
    for (int gg = 0; gg < G128; ++gg) {
        const short* wp = Wf + (size_t)gg * 16 * 512 + lane * 8;
        f32x4 acc[2][8];
#pragma unroll
        for (int q = 0; q < 8; ++q) {
            short8v B0 = *(const short8v*)(wp + (q * 2 + 0) * 512);
            short8v B1 = *(const short8v*)(wp + (q * 2 + 1) * 512);
#pragma unroll
            for (int s = 0; s < 2; ++s) {
                acc[s][q] = __builtin_amdgcn_mfma_f32_16x16x32_bf16(A[s][0], B0,
                                                                    (f32x4){0.f, 0.f, 0.f, 0.f}, 0, 0, 0);
                acc[s][q] = __builtin_amdgcn_mfma_f32_16x16x32_bf16(A[s][1], B1, acc[s][q], 0, 0, 0);
            }
        }
#pragma unroll
        for (int s = 0; s < 2; ++s) {
#pragma unroll
            for (int i = 0; i < 4; ++i) {
                int row = base + s * 16 + kg * 4 + i;
                if (row < nNodes) {
                    uint4 pk;
                    pk.x = (unsigned)(ushort)bfc(acc[s][0][i]) | ((unsigned)(ushort)bfc(acc[s][1][i]) << 16);
                    pk.y = (unsigned)(ushort)bfc(acc[s][2][i]) | ((unsigned)(ushort)bfc(acc[s][3][i]) << 16);
                    pk.z = (unsigned)(ushort)bfc(acc[s][4][i]) | ((unsigned)(ushort)bfc(acc[s][5][i]) << 16);
                    pk.w = (unsigned)(ushort)bfc(acc[s][6][i]) | ((unsigned)(ushort)bfc(acc[s][7][i]) << 16);
                    *reinterpret_cast<uint4*>(yb + (size_t)row * TOUT + gg * 128 + ml * 8) = pk;
                }
            }
        }
    }
}

// ---- edge aggregation. Non-FILTER: scalarized spine — e/bnd/dcur/meta are
// wave-uniform and rooted in readfirstlane/readlane so they live in SGPRs;
// meta becomes s_load, gather base is SALU + saddr-form load; vector pipe
// does only fma + gather issue + flush stores. FILTER: legacy vector path.
template <int OUT, typename OutT, bool ACCUM, bool FILTER, int SHIFT>
__global__ __launch_bounds__(256, 4) void edge_kernel(
    const ushort* __restrict__ yb, const uint2* __restrict__ meta,
    const int* __restrict__ endOff, const float* __restrict__ bias,
    OutT* __restrict__ out, int nNodes, int D, int rtLo) {
    const int lane = threadIdx.x & 63;

    if constexpr (!FILTER) {
        // ---------- scalar path: one dst-range group per wave ----------
        const int wid = (blockIdx.x * blockDim.x + threadIdx.x) >> 6;
        const int o = lane & (OUT - 1);
        const int d0 = wid * D;
        if (d0 >= nNodes) return;
        const int d1 = min(d0 + D, nNodes);
        const float bv = bias[o];

        int bndv = 0x7fffffff;
        if (lane < D) bndv = endOff[min(d0 + lane, nNodes - 1)];
        const int eEnd = __builtin_amdgcn_readlane(bndv, d1 - 1 - d0);
        int e = __builtin_amdgcn_readfirstlane((d0 == 0) ? 0 : endOff[d0 - 1]);
        int dcur = d0;
        int bnd = __builtin_amdgcn_readlane(bndv, 0);
        float acc = 0.f;

        auto gv = [&](unsigned key) -> float {
            const ushort* rowp = (const ushort*)((const char*)yb +
                                                 ((size_t)key << SHIFT));
            return bf2f(rowp[o]);
        };
        auto flushd = [&]() {
            size_t idx = (size_t)dcur * OUT + o;
            if (OUT == 64 || lane < OUT) {
                if constexpr (ACCUM)
                    out[idx] = (OutT)(ushort)bfc(bf2f((ushort)out[idx]) + acc);
                else if constexpr (sizeof(OutT) == 2)
                    out[idx] = (OutT)(ushort)bfc(bv + acc);
                else
                    out[idx] = (OutT)(bv + acc);
            }
            acc = 0.f;
            ++dcur;
            bnd = __builtin_amdgcn_readlane(bndv, dcur - d0);
        };

        if (e < eEnd) {
            const int eL = eEnd - 1;
            uint2 Ma[8], Mb[8];
            float Va[8];
#pragma unroll
            for (int k = 0; k < 8; ++k) Ma[k] = meta[min(e + k, eL)];
#pragma unroll
            for (int k = 0; k < 8; ++k) Mb[k] = meta[min(e + 8 + k, eL)];
#pragma unroll
            for (int k = 0; k < 8; ++k) Va[k] = gv(Ma[k].x);

            const int nFull = (eEnd - e) >> 3;
            for (int blk = 0; blk < nFull; ++blk) {
                float Vb[8];
                uint2 Mc[8];
#pragma unroll
                for (int k = 0; k < 8; ++k) Vb[k] = gv(Mb[k].x);
#pragma unroll
                for (int k = 0; k < 8; ++k) Mc[k] = meta[min(e + 16 + k, eL)];
#pragma unroll
                for (int k = 0; k < 8; ++k) {
                    while (e >= bnd) flushd();
                    acc = fmaf(__uint_as_float(Ma[k].y), Va[k], acc);
                    ++e;
                }
#pragma unroll
                for (int k = 0; k < 8; ++k) { Ma[k] = Mb[k]; Mb[k] = Mc[k]; Va[k] = Vb[k]; }
            }
            const int rem = eEnd - e;
#pragma unroll
            for (int k = 0; k < 8; ++k) {
                if (k < rem) {
                    while (e >= bnd) flushd();
                    acc = fmaf(__uint_as_float(Ma[k].y), Va[k], acc);
                    ++e;
                }
            }
        }
        while (dcur < d1) flushd();
    } else {
        // ---------- legacy vector path (non-fused fallback) ----------
        constexpr int GPW = 64 / OUT;
        const int wid = (blockIdx.x * blockDim.x + threadIdx.x) >> 6;
        const int sub = (GPW == 2) ? (lane >> 5) : 0;
        const int gbase = sub << 5;
        const int gid = wid * GPW + sub;
        const int o = lane & (OUT - 1);
        const int d0 = gid * D;
        if (d0 >= nNodes) return;
        const int d1 = min(d0 + D, nNodes);
        const float bv = bias[o];

        int bndv = 0x7fffffff;
        if (o < D) bndv = endOff[min(d0 + o, nNodes - 1)];
        const int eEnd = __shfl(bndv, gbase + (d1 - 1 - d0));
        int e = (d0 == 0) ? 0 : endOff[d0 - 1];
        int dcur = d0;
        int bnd = __shfl(bndv, gbase);
        float acc = 0.f;

        auto gv = [&](unsigned key) -> float {
            int rr = (int)(key & 7u) - rtLo;
            if ((unsigned)rr >= 4u) return 0.f;
            unsigned off = (((key >> 3) * (unsigned)(4 * OUT)) +
                            (unsigned)rr * OUT + (unsigned)o) << 1;
            return bf2f(*(const ushort*)((const char*)yb + off));
        };
        auto flush = [&](int d, float a) {
            size_t idx = (size_t)d * OUT + o;
            if constexpr (ACCUM) {
                out[idx] = (OutT)(ushort)bfc(bf2f((ushort)out[idx]) + a);
            } else if constexpr (sizeof(OutT) == 2) {
                out[idx] = (OutT)(ushort)bfc(bv + a);
            } else {
                out[idx] = (OutT)(bv + a);
            }
        };

        if (e < eEnd) {
            const int eL = eEnd - 1;
            uint2 Ma[8], Mb[8];
            float Va[8];
#pragma unroll
            for (int k = 0; k < 8; ++k) Ma[k] = meta[min(e + k, eL)];
#pragma unroll
            for (int k = 0; k < 8; ++k) Mb[k] = meta[min(e + 8 + k, eL)];
#pragma unroll
            for (int k = 0; k < 8; ++k) Va[k] = gv(Ma[k].x);
            const int nFull = (eEnd - e) >> 3;
            for (int blk = 0; blk < nFull; ++blk) {
                float Vb[8];
                uint2 Mc[8];
#pragma unroll
                for (int k = 0; k < 8; ++k) Vb[k] = gv(Mb[k].x);
#pragma unroll
                for (int k = 0; k < 8; ++k) Mc[k] = meta[min(e + 16 + k, eL)];
#pragma unroll
                for (int k = 0; k < 8; ++k) {
                    while (e >= bnd) {
                        flush(dcur, acc); acc = 0.f; ++dcur;
                        bnd = __shfl(bndv, gbase + (dcur - d0));
                    }
                    acc = fmaf(__uint_as_float(Ma[k].y), Va[k], acc);
                    ++e;
                }
#pragma unroll
                for (int k = 0; k < 8; ++k) { Ma[k] = Mb[k]; Mb[k] = Mc[k]; Va[k] = Vb[k]; }
            }
            const int rem = eEnd - e;
#pragma unroll
            for (int k = 0; k < 8; ++k) {
                if (k < rem) {
                    while (e >= bnd) {
                        flush(dcur, acc); acc = 0.f; ++dcur;
                        bnd = __shfl(bndv, gbase + (dcur - d0));
                    }
                    acc = fmaf(__uint_as_float(Ma[k].y), Va[k], acc);
                    ++e;
                }
            }
        }
        for (; dcur < d1; ++dcur) {
            flush(dcur, acc);
            acc = 0.f;
        }
    }
}

extern "C" void kernel_launch(void* const* d_in, const int* in_sizes, int n_in,
                              void* d_out, int out_size, void* d_ws, size_t ws_size,
                              hipStream_t stream) {
    const float* emb    = (const float*)d_in[0];
    const float* basis1 = (const float*)d_in[1];
    const float* comp1  = (const float*)d_in[2];
    const float* bias1  = (const float*)d_in[3];
    const float* basis2 = (const float*)d_in[4];
    const float* comp2  = (const float*)d_in[5];
    const float* bias2  = (const float*)d_in[6];
    const int*   src    = (const int*)d_in[7];
    const int*   dst    = (const int*)d_in[8];
    const int*   etype  = (const int*)d_in[9];
    const float* norm   = (const float*)d_in[10];
    float* out = (float*)d_out;

    const int nNodes = in_sizes[0] / 64;   // 200000
    const int nEdges = in_sizes[7];        // 1000000

    const int nBuck = (nNodes + 511) >> BSH;            // 391
    const int chunk = (nEdges + PBLK - 1) / PBLK;       // 3907

    char* ws = (char*)d_ws;
    short* Wf1        = (short*)(ws);                               // 64 KB
    short* Wf2        = (short*)(ws + 65536);                       // 32 KB
    int*   histM      = (int*)(ws + 98304);                         // 400,384 B
    int*   offs       = (int*)(ws + 498688);                        // 400,384 B
    int*   bucketBase = (int*)(ws + 899072);                        // 1,568 B
    int*   endOff     = (int*)(ws + 900640);                        // 800,000 B
    size_t offMeta = 1703936;
    uint2* meta       = (uint2*)(ws + offMeta);                     // 8 MB
    size_t offY = offMeta + (size_t)nEdges * 8;                     // 9,703,936

    const size_t yFused = (size_t)nNodes * 512 * 2;  // 204.8 MB
    const size_t yHalf  = (size_t)nNodes * 256 * 2;  // 102.4 MB
    const size_t h1Sz   = (size_t)nNodes * 64 * 2;   // 25.6 MB
    const bool fused = ws_size >= offY + yFused + h1Sz;
    const size_t ySz = fused ? yFused : yHalf;
    ushort* yB  = (ushort*)(ws + offY);
    ushort* h1b = (ushort*)(ws + offY + ySz);

    // ---- sort (no global atomics, line-dense writes) ----
    wprep_kernel<<<192, 256, 0, stream>>>(basis1, comp1, basis2, comp2, Wf1, Wf2);
    histA_kernel<<<PBLK, 256, 0, stream>>>(dst, histM, nEdges, nBuck, chunk);
    scanA_kernel<<<1, 512, 0, stream>>>(histM, offs, bucketBase, nBuck, PBLK, nEdges);
    part_kernel<<<PBLK, 256, 0, stream>>>(src, dst, etype, norm, offs, meta,
                                          nEdges, nBuck, chunk);
    sortB_kernel<<<nBuck, 256, 0, stream>>>(meta, bucketBase, endOff, nNodes);

    const int tBlocks = (((nNodes + 31) / 32) + 3) / 4;   // 32 nodes per wave
    const int D = 8;
    const int nGroups = (nNodes + D - 1) / D;             // 25000
    const int gBlocks = (nGroups + 3) / 4;                // one group per wave

    if (fused) {
        transform_kernel<4, false><<<tBlocks, 256, 0, stream>>>(emb, Wf1, yB, nNodes);
        edge_kernel<64, ushort, false, false, 7><<<gBlocks, 256, 0, stream>>>(
            yB, meta, endOff, bias1, h1b, nNodes, D, 0);
    } else {
        transform_kernel<2, false><<<tBlocks, 256, 0, stream>>>(emb, Wf1, yB, nNodes);
        edge_kernel<64, ushort, false, true, 0><<<gBlocks, 256, 0, stream>>>(
            yB, meta, endOff, bias1, h1b, nNodes, D, 0);
        transform_kernel<2, false><<<tBlocks, 256, 0, stream>>>(emb, Wf1 + 16384, yB, nNodes);
        edge_kernel<64, ushort, true, true, 0><<<gBlocks, 256, 0, stream>>>(
            yB, meta, endOff, bias1, h1b, nNodes, D, 4);
    }
    // ---- layer 2 ----
    transform_kernel<2, true><<<tBlocks, 256, 0, stream>>>(h1b, Wf2, yB, nNodes);
    edge_kernel<32, float, false, false, 6><<<gBlocks, 256, 0, stream>>>(
        yB, meta, endOff, bias2, out, nNodes, D, 0);
}